// Round 2
// baseline (647.087 us; speedup 1.0000x reference)
//
#include <hip/hip_runtime.h>
#include <cstdint>

typedef unsigned short u16;
typedef __attribute__((ext_vector_type(8))) short s16x8;
typedef __attribute__((ext_vector_type(4))) float f32x4;

#define NTOK 4096
#define DH   64
#define DM   1024
#define NH   16
#define NBH  64      /* 4 batches * 16 heads */
#define MR   16384   /* 4*4096 token rows */

static __device__ __forceinline__ float b2f(u16 u){ return __uint_as_float(((unsigned)u)<<16); }
static __device__ __forceinline__ u16 f2b(float f){
  unsigned u = __float_as_uint(f);
  return (u16)((u + 0x7FFFu + ((u>>16)&1u)) >> 16);   // RNE
}

static __device__ __forceinline__ void gload_lds16(const void* g, void* l) {
  __builtin_amdgcn_global_load_lds(
      (const __attribute__((address_space(1))) unsigned*)(uintptr_t)g,
      (__attribute__((address_space(3))) unsigned*)(uintptr_t)l, 16, 0, 0);
}

static __device__ __forceinline__ s16x8 ld8(const u16* p){ return *(const s16x8*)(const void*)p; }

// ---------------- convert fp32 -> bf16 (flat) ----------------
__global__ __launch_bounds__(256) void k_cvt(const float* __restrict__ in, u16* __restrict__ out, long n4) {
  long i = (long)blockIdx.x*blockDim.x + threadIdx.x;
  const long st = (long)gridDim.x*blockDim.x;
  for (; i < n4; i += st) {
    const float4 v = ((const float4*)in)[i];
    ushort4 o; o.x=f2b(v.x); o.y=f2b(v.y); o.z=f2b(v.z); o.w=f2b(v.w);
    ((ushort4*)out)[i] = o;
  }
}

// ---------------- convert+transpose: f32 [R][C] -> bf16 [C][R] ----------------
__global__ __launch_bounds__(256) void k_cvt_t(const float* __restrict__ in, u16* __restrict__ out, int R, int C) {
  __shared__ float tile[64][65];
  const int tc = blockIdx.x, tr = blockIdx.y;
  const int t = threadIdx.x, cx = t & 63, ry = t >> 6;
  #pragma unroll
  for (int p = 0; p < 16; ++p) {
    const int row = p*4 + ry;
    tile[row][cx] = in[(long)(tr*64 + row)*C + tc*64 + cx];
  }
  __syncthreads();
  #pragma unroll
  for (int p = 0; p < 16; ++p) {
    const int orow = p*4 + ry;
    out[(long)(tc*64 + orow)*R + tr*64 + cx] = f2b(tile[cx][orow]);
  }
}

// ---------------- landmark means of X (fp32, exact path for pinv) ----------------
__global__ __launch_bounds__(256) void k_xlmean(const float* __restrict__ hs, float* __restrict__ Xl) {
  const int row = blockIdx.x;             // b*64 + lm
  const int b = row >> 6, lm = row & 63;
  const float* p = hs + ((long)b*NTOK + lm*64)*DM;
  for (int d = threadIdx.x; d < DM; d += 256) {
    float s = 0.f;
    #pragma unroll 8
    for (int i = 0; i < 64; ++i) s += p[(long)i*DM + d];
    Xl[(long)row*DM + d] = s * (1.0f/64.0f);
  }
}

// ---------------- fp32 projection: q_l/k_l = Xl @ W[:, 0:2048] + b ----------------
__global__ __launch_bounds__(256) void k_lproj(const float* __restrict__ Xl, const float* __restrict__ Wqkv,
                                               const float* __restrict__ bqkv,
                                               float* __restrict__ qlf, float* __restrict__ klf,
                                               u16* __restrict__ qlb, u16* __restrict__ klb) {
  __shared__ __align__(16) float Xs[32][68];
  const int t = threadIdx.x;
  const int wcol = blockIdx.x*256 + t;    // 0..2047
  const int r0 = blockIdx.y*32;
  float acc[32];
  #pragma unroll
  for (int r = 0; r < 32; ++r) acc[r] = 0.f;
  for (int k0 = 0; k0 < 1024; k0 += 64) {
    __syncthreads();
    for (int idx = t; idx < 2048; idx += 256)
      Xs[idx>>6][idx&63] = Xl[(long)(r0 + (idx>>6))*DM + k0 + (idx&63)];
    __syncthreads();
    for (int kk = 0; kk < 64; kk += 4) {
      f32x4 wv;
      #pragma unroll
      for (int j = 0; j < 4; ++j) wv[j] = Wqkv[(long)(k0+kk+j)*3072 + wcol];
      #pragma unroll
      for (int r = 0; r < 32; ++r) {
        const f32x4 xv = *(const f32x4*)&Xs[r][kk];
        acc[r] += xv[0]*wv[0] + xv[1]*wv[1] + xv[2]*wv[2] + xv[3]*wv[3];
      }
    }
  }
  const float bi = bqkv[wcol];
  const int isq = (wcol < 1024) ? 1 : 0;
  const int c2 = wcol & 1023, h = c2 >> 6, dh = c2 & 63;
  for (int r = 0; r < 32; ++r) {
    const int row = r0 + r, b = row >> 6, lm = row & 63;
    float val = acc[r] + bi; if (isq) val *= 0.125f;
    const long o = (((long)b*NH + h)*64 + lm)*64 + dh;
    if (isq) { qlf[o] = val; qlb[o] = f2b(val); }
    else     { klf[o] = val; klb[o] = f2b(val); }
  }
}

// ---------------- GEMM: C = A[M,K] @ Bt[N,K]^T, 128x128 tile, BK=32, 4 waves ----------------
template<int EPI>
__global__ __launch_bounds__(256) void k_gemm_bt(
    const u16* __restrict__ A, const u16* __restrict__ Bt, const float* __restrict__ bias,
    int K, int N, float* __restrict__ outF, u16* __restrict__ outQ, u16* __restrict__ outK, u16* __restrict__ outV)
{
  __shared__ __align__(16) u16 As[128*32];
  __shared__ __align__(16) u16 Bs[128*32];
  const int t = threadIdx.x;
  const int lane = t & 63, wid = t >> 6;
  const int c = lane & 15, g = lane >> 4;
  const long arow0 = (long)blockIdx.x * 128;
  const long brow0 = (long)blockIdx.y * 128;

  f32x4 acc[4][4] = {};

  const int lin0 = t, lin1 = t + 256;
  const int r0 = lin0 >> 2, s0 = lin0 & 3;
  const int r1 = lin1 >> 2, s1 = lin1 & 3;
  const u16* ga0 = A  + (arow0 + r0)*K + s0*8;
  const u16* ga1 = A  + (arow0 + r1)*K + s1*8;
  const u16* gb0 = Bt + (brow0 + r0)*K + s0*8;
  const u16* gb1 = Bt + (brow0 + r1)*K + s1*8;
  char* As_c = (char*)As; char* Bs_c = (char*)Bs;
  const int wr = (wid >> 1) * 64, wc = (wid & 1) * 64;

  for (int k0 = 0; k0 < K; k0 += 32) {
    gload_lds16(ga0 + k0, As_c + lin0*16);
    gload_lds16(ga1 + k0, As_c + lin1*16);
    gload_lds16(gb0 + k0, Bs_c + lin0*16);
    gload_lds16(gb1 + k0, Bs_c + lin1*16);
    __syncthreads();
    s16x8 af[4], bfv[4];
    const int lk = g * 16;
    #pragma unroll
    for (int mi = 0; mi < 4; ++mi) af[mi]  = *(const s16x8*)(As_c + (wr + mi*16 + c)*64 + lk);
    #pragma unroll
    for (int ni = 0; ni < 4; ++ni) bfv[ni] = *(const s16x8*)(Bs_c + (wc + ni*16 + c)*64 + lk);
    #pragma unroll
    for (int mi = 0; mi < 4; ++mi)
      #pragma unroll
      for (int ni = 0; ni < 4; ++ni)
        acc[mi][ni] = __builtin_amdgcn_mfma_f32_16x16x32_bf16(af[mi], bfv[ni], acc[mi][ni], 0, 0, 0);
    __syncthreads();
  }

  if (EPI == 0) {
    const int tensor = (int)(brow0 >> 10);
    u16* dst = (tensor == 0) ? outQ : (tensor == 1) ? outK : outV;
    const float mul = (tensor == 0) ? 0.125f : 1.0f;
    #pragma unroll
    for (int mi = 0; mi < 4; ++mi) {
      const int rowb = wr + mi*16 + g*4;
      #pragma unroll
      for (int ni = 0; ni < 4; ++ni) {
        const long gcol = brow0 + wc + ni*16 + c;
        const int c2 = (int)(gcol & 1023);
        const int head = c2 >> 6, dh = c2 & 63;
        const float bi = bias[gcol];
        #pragma unroll
        for (int r = 0; r < 4; ++r) {
          const long grow = arow0 + rowb + r;
          const int b = (int)(grow >> 12), tok = (int)(grow & 4095);
          dst[(((long)b*NH + head)*NTOK + tok)*DH + dh] = f2b((acc[mi][ni][r] + bi)*mul);
        }
      }
    }
  } else {
    #pragma unroll
    for (int mi = 0; mi < 4; ++mi) {
      const int rowb = wr + mi*16 + g*4;
      #pragma unroll
      for (int ni = 0; ni < 4; ++ni) {
        const long gcol = brow0 + wc + ni*16 + c;
        const float bi = bias[gcol];
        #pragma unroll
        for (int r = 0; r < 4; ++r) {
          const long grow = arow0 + rowb + r;
          outF[grow*N + gcol] = acc[mi][ni][r] + bi;
        }
      }
    }
  }
}

// ---------------- v transpose: [bh][tok][dh] -> [bh][dh][tok] ----------------
__global__ __launch_bounds__(256) void k_vtrans(const u16* __restrict__ v, u16* __restrict__ vt) {
  __shared__ u16 tile[64][65];
  const int bh = blockIdx.x >> 6, tt = blockIdx.x & 63;
  const int t = threadIdx.x, cx = t & 63, ry = t >> 6;
  const u16* vp = v + ((long)bh*NTOK + tt*64)*DH;
  #pragma unroll
  for (int p = 0; p < 16; ++p) { const int row = p*4 + ry; tile[row][cx] = vp[row*DH + cx]; }
  __syncthreads();
  u16* op = vt + (long)bh*DH*NTOK + tt*64;
  #pragma unroll
  for (int p = 0; p < 16; ++p) { const int orow = p*4 + ry; op[(long)orow*NTOK + cx] = tile[cx][orow]; }
}

// ---------------- fp32 LDS 64x64 matmul helpers (stride 68) ----------------
#define PST 68
static __device__ __forceinline__ void mm_nn(const float* A, const float* B, float* C, int t) {
  const int lane = t & 63, j0 = (t >> 6) << 4;
  float acc[16];
  #pragma unroll
  for (int j = 0; j < 16; ++j) acc[j] = 0.f;
  for (int k = 0; k < 64; k += 4) {
    const f32x4 a4 = *(const f32x4*)&A[lane*PST + k];
    #pragma unroll
    for (int dk = 0; dk < 4; ++dk) {
      const float a = a4[dk];
      const float* br = &B[(k + dk)*PST + j0];
      const f32x4 b0 = *(const f32x4*)(br);
      const f32x4 b1 = *(const f32x4*)(br + 4);
      const f32x4 b2 = *(const f32x4*)(br + 8);
      const f32x4 b3 = *(const f32x4*)(br + 12);
      #pragma unroll
      for (int qq = 0; qq < 4; ++qq) {
        acc[qq]    += a*b0[qq]; acc[4+qq]  += a*b1[qq];
        acc[8+qq]  += a*b2[qq]; acc[12+qq] += a*b3[qq];
      }
    }
  }
  #pragma unroll
  for (int j = 0; j < 16; ++j) C[lane*PST + j0 + j] = acc[j];
}
static __device__ __forceinline__ void mm_nt(const float* A, const float* B, float* C, int t) {
  const int lane = t & 63, j0 = (t >> 6) << 4;
  float acc[16];
  #pragma unroll
  for (int j = 0; j < 16; ++j) acc[j] = 0.f;
  for (int k = 0; k < 64; k += 4) {
    const f32x4 a4 = *(const f32x4*)&A[lane*PST + k];
    #pragma unroll
    for (int jj = 0; jj < 16; ++jj) {
      const f32x4 b4 = *(const f32x4*)&B[(j0 + jj)*PST + k];
      acc[jj] += a4[0]*b4[0] + a4[1]*b4[1] + a4[2]*b4[2] + a4[3]*b4[3];
    }
  }
  #pragma unroll
  for (int j = 0; j < 16; ++j) C[lane*PST + j0 + j] = acc[j];
}

// ---------------- sim2 + softmax + Newton-Schulz pinv (all fp32) ----------------
__global__ __launch_bounds__(256) void k_pinv(const float* __restrict__ qlf, const float* __restrict__ klf,
                                              float* __restrict__ a2inv) {
  __shared__ __align__(16) float Xb[64*PST];
  __shared__ __align__(16) float Vb[64*PST];
  __shared__ __align__(16) float T1[64*PST];
  __shared__ __align__(16) float T2[64*PST];
  __shared__ __align__(16) float T3[64*PST];
  const int bh = blockIdx.x, t = threadIdx.x;
  const float* ql = qlf + (long)bh*4096;
  const float* kl = klf + (long)bh*4096;
  for (int i = t; i < 4096; i += 256) { T1[(i>>6)*PST + (i&63)] = ql[i]; T2[(i>>6)*PST + (i&63)] = kl[i]; }
  __syncthreads();
  mm_nt(T1, T2, Xb, t);          // sim2 = q_l @ k_l^T
  __syncthreads();
  if (t < 64) {                  // row softmax (precise exp on the chaotic path)
    float mx = -1e30f;
    for (int j = 0; j < 64; ++j) mx = fmaxf(mx, Xb[t*PST + j]);
    float s = 0.f;
    for (int j = 0; j < 64; ++j) { const float e = expf(Xb[t*PST + j] - mx); Xb[t*PST + j] = e; s += e; }
    const float inv = 1.0f/s;
    for (int j = 0; j < 64; ++j) Xb[t*PST + j] *= inv;
  }
  __syncthreads();
  for (int i = t; i < 4096; i += 256) { const int r = i>>6, cc = i&63; Vb[r*PST+cc] = Xb[r*PST+cc]; }
  __syncthreads();
  for (int it = 0; it < 6; ++it) {
    mm_nn(Xb, Vb, T1, t);  __syncthreads();                  // KV
    for (int i = t; i < 4096; i += 256) { const int r=i>>6, cc=i&63; T2[r*PST+cc] = (r==cc?7.0f:0.0f) - T1[r*PST+cc]; }
    __syncthreads();
    mm_nn(T1, T2, T3, t);  __syncthreads();                  // KV@(7I-KV)
    for (int i = t; i < 4096; i += 256) { const int r=i>>6, cc=i&63; T2[r*PST+cc] = (r==cc?15.0f:0.0f) - T3[r*PST+cc]; }
    __syncthreads();
    mm_nn(T1, T2, T3, t);  __syncthreads();                  // KV@(15I-...)
    for (int i = t; i < 4096; i += 256) { const int r=i>>6, cc=i&63; T2[r*PST+cc] = (r==cc?13.0f:0.0f) - T3[r*PST+cc]; }
    __syncthreads();
    mm_nn(Vb, T2, T3, t);  __syncthreads();                  // V@(13I-...)
    for (int i = t; i < 4096; i += 256) { const int r=i>>6, cc=i&63; Vb[r*PST+cc] = 0.25f*T3[r*PST+cc]; }
    __syncthreads();
  }
  for (int i = t; i < 4096; i += 256) a2inv[(long)bh*4096 + i] = Vb[(i>>6)*PST + (i&63)];
}

// ---------------- attn3 @ v  (flash-style, max-free softmax, per (b,h)) ----------------
__global__ __launch_bounds__(256) void k_attn3v(const u16* __restrict__ qlb, const u16* __restrict__ kk,
                                                const u16* __restrict__ vt, float* __restrict__ z) {
  __shared__ __align__(16) float Zl[4][64][64];
  __shared__ float Sl[4][64];
  __shared__ __align__(16) u16 Pl[4][64][40];   // rows padded to 80B (32 cols used)
  const int bh = blockIdx.x;
  const int t = threadIdx.x, w = t >> 6, lane = t & 63;
  const int c = lane & 15, g = lane >> 4;

  s16x8 aq[4][2];
  const u16* qlp = qlb + (long)bh*4096;
  #pragma unroll
  for (int mi = 0; mi < 4; ++mi)
    #pragma unroll
    for (int ks = 0; ks < 2; ++ks)
      aq[mi][ks] = ld8(qlp + (mi*16 + c)*64 + ks*32 + g*8);

  f32x4 zacc[4][4] = {};
  float sl[4][4] = {};
  const u16* kp = kk + (long)bh*NTOK*DH;
  const u16* vp = vt + (long)bh*DH*NTOK;
  char* pbase = (char*)&Pl[w][0][0];
  const int tok00 = w * 1024;

  for (int it = 0; it < 32; ++it) {
    const int t0 = tok00 + it*32;
    f32x4 sacc[4][2] = {};
    s16x8 kb[2][2];
    #pragma unroll
    for (int cg = 0; cg < 2; ++cg)
      #pragma unroll
      for (int ks = 0; ks < 2; ++ks)
        kb[cg][ks] = ld8(kp + (long)(t0 + cg*16 + c)*64 + ks*32 + g*8);
    #pragma unroll
    for (int cg = 0; cg < 2; ++cg)
      #pragma unroll
      for (int ks = 0; ks < 2; ++ks)
        #pragma unroll
        for (int mi = 0; mi < 4; ++mi)
          sacc[mi][cg] = __builtin_amdgcn_mfma_f32_16x16x32_bf16(aq[mi][ks], kb[cg][ks], sacc[mi][cg], 0, 0, 0);
    #pragma unroll
    for (int mi = 0; mi < 4; ++mi)
      #pragma unroll
      for (int r = 0; r < 4; ++r) {
        const int row = mi*16 + g*4 + r;
        const float p0 = __expf(sacc[mi][0][r]);
        const float p1 = __expf(sacc[mi][1][r]);
        sl[mi][r] += p0 + p1;
        char* base = pbase + row*80;
        *(u16*)(base + c*2)      = f2b(p0);
        *(u16*)(base + 32 + c*2) = f2b(p1);
      }
    s16x8 pa[4];
    #pragma unroll
    for (int mi = 0; mi < 4; ++mi) pa[mi] = *(const s16x8*)(pbase + (mi*16 + c)*80 + g*16);
    #pragma unroll
    for (int ni = 0; ni < 4; ++ni) {
      const s16x8 vb = ld8(vp + (long)(ni*16 + c)*NTOK + t0 + g*8);
      #pragma unroll
      for (int mi = 0; mi < 4; ++mi)
        zacc[mi][ni] = __builtin_amdgcn_mfma_f32_16x16x32_bf16(pa[mi], vb, zacc[mi][ni], 0, 0, 0);
    }
  }
  #pragma unroll
  for (int mi = 0; mi < 4; ++mi)
    #pragma unroll
    for (int r = 0; r < 4; ++r) {
      float s = sl[mi][r];
      s += __shfl_xor(s, 1); s += __shfl_xor(s, 2); s += __shfl_xor(s, 4); s += __shfl_xor(s, 8);
      sl[mi][r] = s;
    }
  #pragma unroll
  for (int mi = 0; mi < 4; ++mi)
    #pragma unroll
    for (int ni = 0; ni < 4; ++ni)
      #pragma unroll
      for (int r = 0; r < 4; ++r)
        Zl[w][mi*16 + g*4 + r][ni*16 + c] = zacc[mi][ni][r];
  if (c == 0)
    #pragma unroll
    for (int mi = 0; mi < 4; ++mi)
      #pragma unroll
      for (int r = 0; r < 4; ++r)
        Sl[w][mi*16 + g*4 + r] = sl[mi][r];
  __syncthreads();
  for (int i = t; i < 4096; i += 256) {
    const int row = i >> 6, dh = i & 63;
    const float zs = Zl[0][row][dh] + Zl[1][row][dh] + Zl[2][row][dh] + Zl[3][row][dh];
    const float ss = Sl[0][row] + Sl[1][row] + Sl[2][row] + Sl[3][row];
    z[(long)bh*4096 + i] = zs / ss;
  }
}

// ---------------- W2^T = (attn2inv @ z)^T  (bf16 out, [dh][lm]) ----------------
__global__ __launch_bounds__(256) void k_w2(const float* __restrict__ a2inv, const float* __restrict__ z,
                                            u16* __restrict__ w2t) {
  __shared__ __align__(16) float Ai[64*PST];
  __shared__ __align__(16) float Zi[64*PST];
  __shared__ __align__(16) float Ci[64*PST];
  const int bh = blockIdx.x, t = threadIdx.x;
  for (int i = t; i < 4096; i += 256) {
    Ai[(i>>6)*PST + (i&63)] = a2inv[(long)bh*4096 + i];
    Zi[(i>>6)*PST + (i&63)] = z[(long)bh*4096 + i];
  }
  __syncthreads();
  mm_nn(Ai, Zi, Ci, t);
  __syncthreads();
  for (int i = t; i < 4096; i += 256) { const int r = i>>6, cc = i&63; w2t[(long)bh*4096 + cc*64 + r] = f2b(Ci[r*PST + cc]); }
}

// ---------------- out_h = softmax(q @ k_l^T) @ W2, fused, writes attnout bf16 ----------------
#define P1ST 144   /* bytes per P row: 64 cols * 2B = 128 data, padded to 144 */
__global__ __launch_bounds__(256) void k_attn1(const u16* __restrict__ q, const u16* __restrict__ klb,
                                               const u16* __restrict__ w2t, u16* __restrict__ ao) {
  __shared__ __align__(16) u16 Pl[4][64][72];
  const int bx = blockIdx.x, bh = bx >> 4, tt = bx & 15;
  const int b = bh >> 4, h = bh & 15;
  const int t = threadIdx.x, w = t >> 6, lane = t & 63;
  const int c = lane & 15, g = lane >> 4;
  const int tok0 = tt*256 + w*64;
  const u16* qp  = q + ((long)bh*NTOK + tok0)*DH;
  const u16* klp = klb + (long)bh*4096;
  const u16* wp  = w2t + (long)bh*4096;
  char* pbase = (char*)&Pl[w][0][0];

  s16x8 aq[4][2], kb[4][2], wb[4][2];
  #pragma unroll
  for (int i = 0; i < 4; ++i)
    #pragma unroll
    for (int ks = 0; ks < 2; ++ks) {
      aq[i][ks] = ld8(qp + (long)(i*16 + c)*DH + ks*32 + g*8);
      kb[i][ks] = ld8(klp + (i*16 + c)*64 + ks*32 + g*8);
      wb[i][ks] = ld8(wp  + (i*16 + c)*64 + ks*32 + g*8);
    }
  f32x4 sacc[4][4] = {};
  #pragma unroll
  for (int ks = 0; ks < 2; ++ks)
    #pragma unroll
    for (int mi = 0; mi < 4; ++mi)
      #pragma unroll
      for (int ni = 0; ni < 4; ++ni)
        sacc[mi][ni] = __builtin_amdgcn_mfma_f32_16x16x32_bf16(aq[mi][ks], kb[ni][ks], sacc[mi][ni], 0, 0, 0);

  float rs[4][4];
  #pragma unroll
  for (int mi = 0; mi < 4; ++mi)
    #pragma unroll
    for (int r = 0; r < 4; ++r) {
      const int row = mi*16 + g*4 + r;
      char* base = pbase + row*P1ST;
      float ssum = 0.f;
      #pragma unroll
      for (int ni = 0; ni < 4; ++ni) {
        const float p = __expf(sacc[mi][ni][r]);
        ssum += p;
        *(u16*)(base + (ni*16 + c)*2) = f2b(p);
      }
      ssum += __shfl_xor(ssum, 1); ssum += __shfl_xor(ssum, 2);
      ssum += __shfl_xor(ssum, 4); ssum += __shfl_xor(ssum, 8);
      rs[mi][r] = ssum;
    }
  __builtin_amdgcn_s_barrier();   // intra-wave store->read; wave-level barrier is enough but cheap
  s16x8 pa[4][2];
  #pragma unroll
  for (int mi = 0; mi < 4; ++mi)
    #pragma unroll
    for (int ks = 0; ks < 2; ++ks)
      pa[mi][ks] = *(const s16x8*)(pbase + (mi*16 + c)*P1ST + ks*64 + g*16);
  f32x4 oacc[4][4] = {};
  #pragma unroll
  for (int ks = 0; ks < 2; ++ks)
    #pragma unroll
    for (int mi = 0; mi < 4; ++mi)
      #pragma unroll
      for (int ni = 0; ni < 4; ++ni)
        oacc[mi][ni] = __builtin_amdgcn_mfma_f32_16x16x32_bf16(pa[mi][ks], wb[ni][ks], oacc[mi][ni], 0, 0, 0);

  u16* op = ao + (long)b*NTOK*DM + (long)h*64;
  #pragma unroll
  for (int mi = 0; mi < 4; ++mi)
    #pragma unroll
    for (int r = 0; r < 4; ++r) {
      const int tok = tok0 + mi*16 + g*4 + r;
      const float inv = 1.0f / rs[mi][r];
      #pragma unroll
      for (int ni = 0; ni < 4; ++ni)
        op[(long)tok*DM + ni*16 + c] = f2b(oacc[mi][ni][r] * inv);
    }
}

extern "C" void kernel_launch(void* const* d_in, const int* in_sizes, int n_in,
                              void* d_out, int out_size, void* d_ws, size_t ws_size,
                              hipStream_t stream) {
  const float* hs   = (const float*)d_in[0];
  const float* Wqkv = (const float*)d_in[1];
  const float* bqkv = (const float*)d_in[2];
  const float* Wout = (const float*)d_in[3];
  const float* bout = (const float*)d_in[4];
  float* out = (float*)d_out;
  char* w = (char*)d_ws;

  u16*  Xb    = (u16*)(w);
  u16*  WqkvT = (u16*)(w + 33554432L);
  u16*  WoutT = (u16*)(w + 39845888L);
  u16*  q     = (u16*)(w + 41943040L);
  u16*  k     = (u16*)(w + 75497472L);
  u16*  v     = (u16*)(w + 109051904L);
  u16*  vt    = (u16*)(w + 142606336L);
  float* Xl   = (float*)(w + 142606336L);  // aliases vt: consumed before k_vtrans writes
  float* qlf  = (float*)(w + 176160768L);
  float* klf  = (float*)(w + 177209344L);
  u16*  qlb   = (u16*)(w + 178257920L);
  u16*  klb   = (u16*)(w + 178782208L);
  float* a2i  = (float*)(w + 179306496L);
  float* z    = (float*)(w + 180355072L);
  u16*  w2t   = (u16*)(w + 181403648L);
  u16*  ao    = (u16*)(w + 181927936L);

  k_cvt<<<2048, 256, 0, stream>>>(hs, Xb, 4194304L);
  k_cvt_t<<<dim3(48,16), 256, 0, stream>>>(Wqkv, WqkvT, 1024, 3072);
  k_cvt_t<<<dim3(16,16), 256, 0, stream>>>(Wout, WoutT, 1024, 1024);
  k_xlmean<<<256, 256, 0, stream>>>(hs, Xl);
  k_lproj<<<dim3(8,8), 256, 0, stream>>>(Xl, Wqkv, bqkv, qlf, klf, qlb, klb);
  k_gemm_bt<0><<<dim3(128,24), 256, 0, stream>>>(Xb, WqkvT, bqkv, 1024, 3072, nullptr, q, k, v);
  k_vtrans<<<4096, 256, 0, stream>>>(v, vt);
  k_pinv<<<64, 256, 0, stream>>>(qlf, klf, a2i);
  k_attn3v<<<64, 256, 0, stream>>>(qlb, k, vt, z);
  k_w2<<<64, 256, 0, stream>>>(a2i, z, w2t);
  k_attn1<<<1024, 256, 0, stream>>>(q, klb, w2t, ao);
  k_gemm_bt<1><<<dim3(128,8), 256, 0, stream>>>(ao, WoutT, bout, 1024, 1024, out, nullptr, nullptr, nullptr);
}

// Round 3
// 468.998 us; speedup vs baseline: 1.3797x; 1.3797x over previous
//
#include <hip/hip_runtime.h>
#include <cstdint>

typedef unsigned short u16;
typedef __attribute__((ext_vector_type(8))) short s16x8;
typedef __attribute__((ext_vector_type(4))) float f32x4;

#define NTOK 4096
#define DH   64
#define DM   1024
#define NH   16
#define NBH  64      /* 4 batches * 16 heads */
#define MR   16384   /* 4*4096 token rows */

static __device__ __forceinline__ float b2f(u16 u){ return __uint_as_float(((unsigned)u)<<16); }
static __device__ __forceinline__ u16 f2b(float f){
  unsigned u = __float_as_uint(f);
  return (u16)((u + 0x7FFFu + ((u>>16)&1u)) >> 16);   // RNE
}

static __device__ __forceinline__ void gload_lds16(const void* g, void* l) {
  __builtin_amdgcn_global_load_lds(
      (const __attribute__((address_space(1))) unsigned*)(uintptr_t)g,
      (__attribute__((address_space(3))) unsigned*)(uintptr_t)l, 16, 0, 0);
}

static __device__ __forceinline__ s16x8 ld8(const u16* p){ return *(const s16x8*)(const void*)p; }

// ---------------- convert fp32 -> bf16 (flat) ----------------
__global__ __launch_bounds__(256) void k_cvt(const float* __restrict__ in, u16* __restrict__ out, long n4) {
  long i = (long)blockIdx.x*blockDim.x + threadIdx.x;
  const long st = (long)gridDim.x*blockDim.x;
  for (; i < n4; i += st) {
    const float4 v = ((const float4*)in)[i];
    ushort4 o; o.x=f2b(v.x); o.y=f2b(v.y); o.z=f2b(v.z); o.w=f2b(v.w);
    ((ushort4*)out)[i] = o;
  }
}

// ---------------- convert+transpose: f32 [R][C] -> bf16 [C][R] ----------------
__global__ __launch_bounds__(256) void k_cvt_t(const float* __restrict__ in, u16* __restrict__ out, int R, int C) {
  __shared__ float tile[64][65];
  const int tc = blockIdx.x, tr = blockIdx.y;
  const int t = threadIdx.x, cx = t & 63, ry = t >> 6;
  #pragma unroll
  for (int p = 0; p < 16; ++p) {
    const int row = p*4 + ry;
    tile[row][cx] = in[(long)(tr*64 + row)*C + tc*64 + cx];
  }
  __syncthreads();
  #pragma unroll
  for (int p = 0; p < 16; ++p) {
    const int orow = p*4 + ry;
    out[(long)(tc*64 + orow)*R + tr*64 + cx] = f2b(tile[cx][orow]);
  }
}

// ---------------- landmark means of X (fp32, exact path for pinv) ----------------
// grid (256 rows, 4 d-chunks); each thread owns one output column
__global__ __launch_bounds__(256) void k_xlmean(const float* __restrict__ hs, float* __restrict__ Xl) {
  const int row = blockIdx.x;             // b*64 + lm
  const int b = row >> 6, lm = row & 63;
  const int d = blockIdx.y*256 + threadIdx.x;
  const float* p = hs + ((long)b*NTOK + lm*64)*DM + d;
  float s = 0.f;
  #pragma unroll 16
  for (int i = 0; i < 64; ++i) s += p[(long)i*DM];
  Xl[(long)row*DM + d] = s * (1.0f/64.0f);
}

// ---------------- fp32 projection, K-split: psum[z][row][col] partials ----------------
// grid (8 col-tiles, 8 row-tiles, 8 K-slices); block = 256 threads, 1 col/thread, 32 rows
__global__ __launch_bounds__(256) void k_lproj2(const float* __restrict__ Xl, const float* __restrict__ Wqkv,
                                                float* __restrict__ psum) {
  __shared__ __align__(16) float Xs[32][68];
  const int t = threadIdx.x;
  const int wcol = blockIdx.x*256 + t;    // 0..2047
  const int r0 = blockIdx.y*32;
  const int kbase = blockIdx.z*128;
  float acc[32];
  #pragma unroll
  for (int r = 0; r < 32; ++r) acc[r] = 0.f;
  for (int k0 = kbase; k0 < kbase + 128; k0 += 64) {
    __syncthreads();
    for (int idx = t; idx < 2048; idx += 256)
      Xs[idx>>6][idx&63] = Xl[(long)(r0 + (idx>>6))*DM + k0 + (idx&63)];
    __syncthreads();
    for (int kk = 0; kk < 64; kk += 4) {
      f32x4 wv;
      #pragma unroll
      for (int j = 0; j < 4; ++j) wv[j] = Wqkv[(long)(k0+kk+j)*3072 + wcol];
      #pragma unroll
      for (int r = 0; r < 32; ++r) {
        const f32x4 xv = *(const f32x4*)&Xs[r][kk];
        acc[r] += xv[0]*wv[0] + xv[1]*wv[1] + xv[2]*wv[2] + xv[3]*wv[3];
      }
    }
  }
  float* po = psum + ((long)blockIdx.z*256 + r0)*2048 + wcol;
  #pragma unroll
  for (int r = 0; r < 32; ++r) po[(long)r*2048] = acc[r];
}

// ---------------- reduce K-slices + bias + scale -> qlf/klf/qlb/klb ----------------
__global__ __launch_bounds__(256) void k_lreduce(const float* __restrict__ psum, const float* __restrict__ bqkv,
                                                 float* __restrict__ qlf, float* __restrict__ klf,
                                                 u16* __restrict__ qlb, u16* __restrict__ klb) {
  const long idx = (long)blockIdx.x*256 + threadIdx.x;   // 0..524287
  const int row = (int)(idx >> 11), col = (int)(idx & 2047);
  float s = 0.f;
  #pragma unroll
  for (int z = 0; z < 8; ++z) s += psum[((long)z*256 + row)*2048 + col];
  const int isq = (col < 1024) ? 1 : 0;
  float val = s + bqkv[col];
  if (isq) val *= 0.125f;
  const int b = row >> 6, lm = row & 63;
  const int c2 = col & 1023, h = c2 >> 6, dh = c2 & 63;
  const long o = (((long)b*NH + h)*64 + lm)*64 + dh;
  if (isq) { qlf[o] = val; qlb[o] = f2b(val); }
  else     { klf[o] = val; klb[o] = f2b(val); }
}

// ---------------- GEMM: C = A[M,K] @ Bt[N,K]^T, 128x128 tile, BK=32, 4 waves ----------------
template<int EPI>
__global__ __launch_bounds__(256) void k_gemm_bt(
    const u16* __restrict__ A, const u16* __restrict__ Bt, const float* __restrict__ bias,
    int K, int N, float* __restrict__ outF, u16* __restrict__ outQ, u16* __restrict__ outK, u16* __restrict__ outV)
{
  __shared__ __align__(16) u16 As[128*32];
  __shared__ __align__(16) u16 Bs[128*32];
  const int t = threadIdx.x;
  const int lane = t & 63, wid = t >> 6;
  const int c = lane & 15, g = lane >> 4;
  const long arow0 = (long)blockIdx.x * 128;
  const long brow0 = (long)blockIdx.y * 128;

  f32x4 acc[4][4] = {};

  const int lin0 = t, lin1 = t + 256;
  const int r0 = lin0 >> 2, s0 = lin0 & 3;
  const int r1 = lin1 >> 2, s1 = lin1 & 3;
  const u16* ga0 = A  + (arow0 + r0)*K + s0*8;
  const u16* ga1 = A  + (arow0 + r1)*K + s1*8;
  const u16* gb0 = Bt + (brow0 + r0)*K + s0*8;
  const u16* gb1 = Bt + (brow0 + r1)*K + s1*8;
  char* As_c = (char*)As; char* Bs_c = (char*)Bs;
  const int wr = (wid >> 1) * 64, wc = (wid & 1) * 64;

  for (int k0 = 0; k0 < K; k0 += 32) {
    gload_lds16(ga0 + k0, As_c + lin0*16);
    gload_lds16(ga1 + k0, As_c + lin1*16);
    gload_lds16(gb0 + k0, Bs_c + lin0*16);
    gload_lds16(gb1 + k0, Bs_c + lin1*16);
    __syncthreads();
    s16x8 af[4], bfv[4];
    const int lk = g * 16;
    #pragma unroll
    for (int mi = 0; mi < 4; ++mi) af[mi]  = *(const s16x8*)(As_c + (wr + mi*16 + c)*64 + lk);
    #pragma unroll
    for (int ni = 0; ni < 4; ++ni) bfv[ni] = *(const s16x8*)(Bs_c + (wc + ni*16 + c)*64 + lk);
    #pragma unroll
    for (int mi = 0; mi < 4; ++mi)
      #pragma unroll
      for (int ni = 0; ni < 4; ++ni)
        acc[mi][ni] = __builtin_amdgcn_mfma_f32_16x16x32_bf16(af[mi], bfv[ni], acc[mi][ni], 0, 0, 0);
    __syncthreads();
  }

  if (EPI == 0) {
    const int tensor = (int)(brow0 >> 10);
    u16* dst = (tensor == 0) ? outQ : (tensor == 1) ? outK : outV;
    const float mul = (tensor == 0) ? 0.125f : 1.0f;
    #pragma unroll
    for (int mi = 0; mi < 4; ++mi) {
      const int rowb = wr + mi*16 + g*4;
      #pragma unroll
      for (int ni = 0; ni < 4; ++ni) {
        const long gcol = brow0 + wc + ni*16 + c;
        const int c2 = (int)(gcol & 1023);
        const int head = c2 >> 6, dh = c2 & 63;
        const float bi = bias[gcol];
        #pragma unroll
        for (int r = 0; r < 4; ++r) {
          const long grow = arow0 + rowb + r;
          const int b = (int)(grow >> 12), tok = (int)(grow & 4095);
          dst[(((long)b*NH + head)*NTOK + tok)*DH + dh] = f2b((acc[mi][ni][r] + bi)*mul);
        }
      }
    }
  } else {
    #pragma unroll
    for (int mi = 0; mi < 4; ++mi) {
      const int rowb = wr + mi*16 + g*4;
      #pragma unroll
      for (int ni = 0; ni < 4; ++ni) {
        const long gcol = brow0 + wc + ni*16 + c;
        const float bi = bias[gcol];
        #pragma unroll
        for (int r = 0; r < 4; ++r) {
          const long grow = arow0 + rowb + r;
          outF[grow*N + gcol] = acc[mi][ni][r] + bi;
        }
      }
    }
  }
}

// ---------------- v transpose: [bh][tok][dh] -> [bh][dh][tok] ----------------
__global__ __launch_bounds__(256) void k_vtrans(const u16* __restrict__ v, u16* __restrict__ vt) {
  __shared__ u16 tile[64][65];
  const int bh = blockIdx.x >> 6, tt = blockIdx.x & 63;
  const int t = threadIdx.x, cx = t & 63, ry = t >> 6;
  const u16* vp = v + ((long)bh*NTOK + tt*64)*DH;
  #pragma unroll
  for (int p = 0; p < 16; ++p) { const int row = p*4 + ry; tile[row][cx] = vp[row*DH + cx]; }
  __syncthreads();
  u16* op = vt + (long)bh*DH*NTOK + tt*64;
  #pragma unroll
  for (int p = 0; p < 16; ++p) { const int orow = p*4 + ry; op[(long)orow*NTOK + cx] = tile[cx][orow]; }
}

// ---------------- fp32 LDS 64x64 matmul helpers (stride 68) ----------------
#define PST 68
static __device__ __forceinline__ void mm_nn(const float* A, const float* B, float* C, int t) {
  const int lane = t & 63, j0 = (t >> 6) << 4;
  float acc[16];
  #pragma unroll
  for (int j = 0; j < 16; ++j) acc[j] = 0.f;
  for (int k = 0; k < 64; k += 4) {
    const f32x4 a4 = *(const f32x4*)&A[lane*PST + k];
    #pragma unroll
    for (int dk = 0; dk < 4; ++dk) {
      const float a = a4[dk];
      const float* br = &B[(k + dk)*PST + j0];
      const f32x4 b0 = *(const f32x4*)(br);
      const f32x4 b1 = *(const f32x4*)(br + 4);
      const f32x4 b2 = *(const f32x4*)(br + 8);
      const f32x4 b3 = *(const f32x4*)(br + 12);
      #pragma unroll
      for (int qq = 0; qq < 4; ++qq) {
        acc[qq]    += a*b0[qq]; acc[4+qq]  += a*b1[qq];
        acc[8+qq]  += a*b2[qq]; acc[12+qq] += a*b3[qq];
      }
    }
  }
  #pragma unroll
  for (int j = 0; j < 16; ++j) C[lane*PST + j0 + j] = acc[j];
}
static __device__ __forceinline__ void mm_nt(const float* A, const float* B, float* C, int t) {
  const int lane = t & 63, j0 = (t >> 6) << 4;
  float acc[16];
  #pragma unroll
  for (int j = 0; j < 16; ++j) acc[j] = 0.f;
  for (int k = 0; k < 64; k += 4) {
    const f32x4 a4 = *(const f32x4*)&A[lane*PST + k];
    #pragma unroll
    for (int jj = 0; jj < 16; ++jj) {
      const f32x4 b4 = *(const f32x4*)&B[(j0 + jj)*PST + k];
      acc[jj] += a4[0]*b4[0] + a4[1]*b4[1] + a4[2]*b4[2] + a4[3]*b4[3];
    }
  }
  #pragma unroll
  for (int j = 0; j < 16; ++j) C[lane*PST + j0 + j] = acc[j];
}

// ---------------- sim2 + softmax + Newton-Schulz pinv (all fp32) ----------------
__global__ __launch_bounds__(256) void k_pinv(const float* __restrict__ qlf, const float* __restrict__ klf,
                                              float* __restrict__ a2inv) {
  __shared__ __align__(16) float Xb[64*PST];
  __shared__ __align__(16) float Vb[64*PST];
  __shared__ __align__(16) float T1[64*PST];
  __shared__ __align__(16) float T2[64*PST];
  __shared__ __align__(16) float T3[64*PST];
  const int bh = blockIdx.x, t = threadIdx.x;
  const float* ql = qlf + (long)bh*4096;
  const float* kl = klf + (long)bh*4096;
  for (int i = t; i < 4096; i += 256) { T1[(i>>6)*PST + (i&63)] = ql[i]; T2[(i>>6)*PST + (i&63)] = kl[i]; }
  __syncthreads();
  mm_nt(T1, T2, Xb, t);          // sim2 = q_l @ k_l^T
  __syncthreads();
  if (t < 64) {                  // row softmax (precise exp on the chaotic path)
    float mx = -1e30f;
    for (int j = 0; j < 64; ++j) mx = fmaxf(mx, Xb[t*PST + j]);
    float s = 0.f;
    for (int j = 0; j < 64; ++j) { const float e = expf(Xb[t*PST + j] - mx); Xb[t*PST + j] = e; s += e; }
    const float inv = 1.0f/s;
    for (int j = 0; j < 64; ++j) Xb[t*PST + j] *= inv;
  }
  __syncthreads();
  for (int i = t; i < 4096; i += 256) { const int r = i>>6, cc = i&63; Vb[r*PST+cc] = Xb[r*PST+cc]; }
  __syncthreads();
  for (int it = 0; it < 6; ++it) {
    mm_nn(Xb, Vb, T1, t);  __syncthreads();                  // KV
    for (int i = t; i < 4096; i += 256) { const int r=i>>6, cc=i&63; T2[r*PST+cc] = (r==cc?7.0f:0.0f) - T1[r*PST+cc]; }
    __syncthreads();
    mm_nn(T1, T2, T3, t);  __syncthreads();                  // KV@(7I-KV)
    for (int i = t; i < 4096; i += 256) { const int r=i>>6, cc=i&63; T2[r*PST+cc] = (r==cc?15.0f:0.0f) - T3[r*PST+cc]; }
    __syncthreads();
    mm_nn(T1, T2, T3, t);  __syncthreads();                  // KV@(15I-...)
    for (int i = t; i < 4096; i += 256) { const int r=i>>6, cc=i&63; T2[r*PST+cc] = (r==cc?13.0f:0.0f) - T3[r*PST+cc]; }
    __syncthreads();
    mm_nn(Vb, T2, T3, t);  __syncthreads();                  // V@(13I-...)
    for (int i = t; i < 4096; i += 256) { const int r=i>>6, cc=i&63; Vb[r*PST+cc] = 0.25f*T3[r*PST+cc]; }
    __syncthreads();
  }
  for (int i = t; i < 4096; i += 256) a2inv[(long)bh*4096 + i] = Vb[(i>>6)*PST + (i&63)];
}

// ---------------- attn3 @ v  (flash-style, max-free softmax, per (b,h)) ----------------
__global__ __launch_bounds__(256) void k_attn3v(const u16* __restrict__ qlb, const u16* __restrict__ kk,
                                                const u16* __restrict__ vt, float* __restrict__ z) {
  __shared__ __align__(16) float Zl[4][64][64];
  __shared__ float Sl[4][64];
  __shared__ __align__(16) u16 Pl[4][64][40];   // rows padded to 80B (32 cols used)
  const int bh = blockIdx.x;
  const int t = threadIdx.x, w = t >> 6, lane = t & 63;
  const int c = lane & 15, g = lane >> 4;

  s16x8 aq[4][2];
  const u16* qlp = qlb + (long)bh*4096;
  #pragma unroll
  for (int mi = 0; mi < 4; ++mi)
    #pragma unroll
    for (int ks = 0; ks < 2; ++ks)
      aq[mi][ks] = ld8(qlp + (mi*16 + c)*64 + ks*32 + g*8);

  f32x4 zacc[4][4] = {};
  float sl[4][4] = {};
  const u16* kp = kk + (long)bh*NTOK*DH;
  const u16* vp = vt + (long)bh*DH*NTOK;
  char* pbase = (char*)&Pl[w][0][0];
  const int tok00 = w * 1024;

  for (int it = 0; it < 32; ++it) {
    const int t0 = tok00 + it*32;
    f32x4 sacc[4][2] = {};
    s16x8 kb[2][2];
    #pragma unroll
    for (int cg = 0; cg < 2; ++cg)
      #pragma unroll
      for (int ks = 0; ks < 2; ++ks)
        kb[cg][ks] = ld8(kp + (long)(t0 + cg*16 + c)*64 + ks*32 + g*8);
    #pragma unroll
    for (int cg = 0; cg < 2; ++cg)
      #pragma unroll
      for (int ks = 0; ks < 2; ++ks)
        #pragma unroll
        for (int mi = 0; mi < 4; ++mi)
          sacc[mi][cg] = __builtin_amdgcn_mfma_f32_16x16x32_bf16(aq[mi][ks], kb[cg][ks], sacc[mi][cg], 0, 0, 0);
    #pragma unroll
    for (int mi = 0; mi < 4; ++mi)
      #pragma unroll
      for (int r = 0; r < 4; ++r) {
        const int row = mi*16 + g*4 + r;
        const float p0 = __expf(sacc[mi][0][r]);
        const float p1 = __expf(sacc[mi][1][r]);
        sl[mi][r] += p0 + p1;
        char* base = pbase + row*80;
        *(u16*)(base + c*2)      = f2b(p0);
        *(u16*)(base + 32 + c*2) = f2b(p1);
      }
    s16x8 pa[4];
    #pragma unroll
    for (int mi = 0; mi < 4; ++mi) pa[mi] = *(const s16x8*)(pbase + (mi*16 + c)*80 + g*16);
    #pragma unroll
    for (int ni = 0; ni < 4; ++ni) {
      const s16x8 vb = ld8(vp + (long)(ni*16 + c)*NTOK + t0 + g*8);
      #pragma unroll
      for (int mi = 0; mi < 4; ++mi)
        zacc[mi][ni] = __builtin_amdgcn_mfma_f32_16x16x32_bf16(pa[mi], vb, zacc[mi][ni], 0, 0, 0);
    }
  }
  #pragma unroll
  for (int mi = 0; mi < 4; ++mi)
    #pragma unroll
    for (int r = 0; r < 4; ++r) {
      float s = sl[mi][r];
      s += __shfl_xor(s, 1); s += __shfl_xor(s, 2); s += __shfl_xor(s, 4); s += __shfl_xor(s, 8);
      sl[mi][r] = s;
    }
  #pragma unroll
  for (int mi = 0; mi < 4; ++mi)
    #pragma unroll
    for (int ni = 0; ni < 4; ++ni)
      #pragma unroll
      for (int r = 0; r < 4; ++r)
        Zl[w][mi*16 + g*4 + r][ni*16 + c] = zacc[mi][ni][r];
  if (c == 0)
    #pragma unroll
    for (int mi = 0; mi < 4; ++mi)
      #pragma unroll
      for (int r = 0; r < 4; ++r)
        Sl[w][mi*16 + g*4 + r] = sl[mi][r];
  __syncthreads();
  for (int i = t; i < 4096; i += 256) {
    const int row = i >> 6, dh = i & 63;
    const float zs = Zl[0][row][dh] + Zl[1][row][dh] + Zl[2][row][dh] + Zl[3][row][dh];
    const float ss = Sl[0][row] + Sl[1][row] + Sl[2][row] + Sl[3][row];
    z[(long)bh*4096 + i] = zs / ss;
  }
}

// ---------------- W2^T = (attn2inv @ z)^T  (bf16 out, [dh][lm]) ----------------
__global__ __launch_bounds__(256) void k_w2(const float* __restrict__ a2inv, const float* __restrict__ z,
                                            u16* __restrict__ w2t) {
  __shared__ __align__(16) float Ai[64*PST];
  __shared__ __align__(16) float Zi[64*PST];
  __shared__ __align__(16) float Ci[64*PST];
  const int bh = blockIdx.x, t = threadIdx.x;
  for (int i = t; i < 4096; i += 256) {
    Ai[(i>>6)*PST + (i&63)] = a2inv[(long)bh*4096 + i];
    Zi[(i>>6)*PST + (i&63)] = z[(long)bh*4096 + i];
  }
  __syncthreads();
  mm_nn(Ai, Zi, Ci, t);
  __syncthreads();
  for (int i = t; i < 4096; i += 256) { const int r = i>>6, cc = i&63; w2t[(long)bh*4096 + cc*64 + r] = f2b(Ci[r*PST + cc]); }
}

// ---------------- out_h = softmax(q @ k_l^T) @ W2, fused, writes attnout bf16 ----------------
#define P1ST 144   /* bytes per P row: 64 cols * 2B = 128 data, padded to 144 */
__global__ __launch_bounds__(256) void k_attn1(const u16* __restrict__ q, const u16* __restrict__ klb,
                                               const u16* __restrict__ w2t, u16* __restrict__ ao) {
  __shared__ __align__(16) u16 Pl[4][64][72];
  const int bx = blockIdx.x, bh = bx >> 4, tt = bx & 15;
  const int b = bh >> 4, h = bh & 15;
  const int t = threadIdx.x, w = t >> 6, lane = t & 63;
  const int c = lane & 15, g = lane >> 4;
  const int tok0 = tt*256 + w*64;
  const u16* qp  = q + ((long)bh*NTOK + tok0)*DH;
  const u16* klp = klb + (long)bh*4096;
  const u16* wp  = w2t + (long)bh*4096;
  char* pbase = (char*)&Pl[w][0][0];

  s16x8 aq[4][2], kb[4][2], wb[4][2];
  #pragma unroll
  for (int i = 0; i < 4; ++i)
    #pragma unroll
    for (int ks = 0; ks < 2; ++ks) {
      aq[i][ks] = ld8(qp + (long)(i*16 + c)*DH + ks*32 + g*8);
      kb[i][ks] = ld8(klp + (i*16 + c)*64 + ks*32 + g*8);
      wb[i][ks] = ld8(wp  + (i*16 + c)*64 + ks*32 + g*8);
    }
  f32x4 sacc[4][4] = {};
  #pragma unroll
  for (int ks = 0; ks < 2; ++ks)
    #pragma unroll
    for (int mi = 0; mi < 4; ++mi)
      #pragma unroll
      for (int ni = 0; ni < 4; ++ni)
        sacc[mi][ni] = __builtin_amdgcn_mfma_f32_16x16x32_bf16(aq[mi][ks], kb[ni][ks], sacc[mi][ni], 0, 0, 0);

  float rs[4][4];
  #pragma unroll
  for (int mi = 0; mi < 4; ++mi)
    #pragma unroll
    for (int r = 0; r < 4; ++r) {
      const int row = mi*16 + g*4 + r;
      char* base = pbase + row*P1ST;
      float ssum = 0.f;
      #pragma unroll
      for (int ni = 0; ni < 4; ++ni) {
        const float p = __expf(sacc[mi][ni][r]);
        ssum += p;
        *(u16*)(base + (ni*16 + c)*2) = f2b(p);
      }
      ssum += __shfl_xor(ssum, 1); ssum += __shfl_xor(ssum, 2);
      ssum += __shfl_xor(ssum, 4); ssum += __shfl_xor(ssum, 8);
      rs[mi][r] = ssum;
    }
  __builtin_amdgcn_s_barrier();   // intra-wave store->read ordering
  s16x8 pa[4][2];
  #pragma unroll
  for (int mi = 0; mi < 4; ++mi)
    #pragma unroll
    for (int ks = 0; ks < 2; ++ks)
      pa[mi][ks] = *(const s16x8*)(pbase + (mi*16 + c)*P1ST + ks*64 + g*16);
  f32x4 oacc[4][4] = {};
  #pragma unroll
  for (int ks = 0; ks < 2; ++ks)
    #pragma unroll
    for (int mi = 0; mi < 4; ++mi)
      #pragma unroll
      for (int ni = 0; ni < 4; ++ni)
        oacc[mi][ni] = __builtin_amdgcn_mfma_f32_16x16x32_bf16(pa[mi][ks], wb[ni][ks], oacc[mi][ni], 0, 0, 0);

  u16* op = ao + (long)b*NTOK*DM + (long)h*64;
  #pragma unroll
  for (int mi = 0; mi < 4; ++mi)
    #pragma unroll
    for (int r = 0; r < 4; ++r) {
      const int tok = tok0 + mi*16 + g*4 + r;
      const float inv = 1.0f / rs[mi][r];
      #pragma unroll
      for (int ni = 0; ni < 4; ++ni)
        op[(long)tok*DM + ni*16 + c] = f2b(oacc[mi][ni][r] * inv);
    }
}

extern "C" void kernel_launch(void* const* d_in, const int* in_sizes, int n_in,
                              void* d_out, int out_size, void* d_ws, size_t ws_size,
                              hipStream_t stream) {
  const float* hs   = (const float*)d_in[0];
  const float* Wqkv = (const float*)d_in[1];
  const float* bqkv = (const float*)d_in[2];
  const float* Wout = (const float*)d_in[3];
  const float* bout = (const float*)d_in[4];
  float* out = (float*)d_out;
  char* w = (char*)d_ws;

  u16*  Xb    = (u16*)(w);
  u16*  WqkvT = (u16*)(w + 33554432L);
  u16*  WoutT = (u16*)(w + 39845888L);
  u16*  q     = (u16*)(w + 41943040L);
  float* psum = (float*)(w + 41943040L);   // aliases q: consumed by k_lreduce before gemm writes q
  u16*  k     = (u16*)(w + 75497472L);
  u16*  v     = (u16*)(w + 109051904L);
  u16*  vt    = (u16*)(w + 142606336L);
  float* Xl   = (float*)(w + 142606336L);  // aliases vt: consumed before k_vtrans writes
  float* qlf  = (float*)(w + 176160768L);
  float* klf  = (float*)(w + 177209344L);
  u16*  qlb   = (u16*)(w + 178257920L);
  u16*  klb   = (u16*)(w + 178782208L);
  float* a2i  = (float*)(w + 179306496L);
  float* z    = (float*)(w + 180355072L);
  u16*  w2t   = (u16*)(w + 181403648L);
  u16*  ao    = (u16*)(w + 181927936L);

  k_cvt<<<2048, 256, 0, stream>>>(hs, Xb, 4194304L);
  k_cvt_t<<<dim3(48,16), 256, 0, stream>>>(Wqkv, WqkvT, 1024, 3072);
  k_cvt_t<<<dim3(16,16), 256, 0, stream>>>(Wout, WoutT, 1024, 1024);
  k_xlmean<<<dim3(256,4), 256, 0, stream>>>(hs, Xl);
  k_lproj2<<<dim3(8,8,8), 256, 0, stream>>>(Xl, Wqkv, psum);
  k_lreduce<<<2048, 256, 0, stream>>>(psum, bqkv, qlf, klf, qlb, klb);
  k_gemm_bt<0><<<dim3(128,24), 256, 0, stream>>>(Xb, WqkvT, bqkv, 1024, 3072, nullptr, q, k, v);
  k_vtrans<<<4096, 256, 0, stream>>>(v, vt);
  k_pinv<<<64, 256, 0, stream>>>(qlf, klf, a2i);
  k_attn3v<<<64, 256, 0, stream>>>(qlb, k, vt, z);
  k_w2<<<64, 256, 0, stream>>>(a2i, z, w2t);
  k_attn1<<<1024, 256, 0, stream>>>(q, klb, w2t, ao);
  k_gemm_bt<1><<<dim3(128,8), 256, 0, stream>>>(ao, WoutT, bout, 1024, 1024, out, nullptr, nullptr, nullptr);
}

// Round 4
// 385.864 us; speedup vs baseline: 1.6770x; 1.2154x over previous
//
#include <hip/hip_runtime.h>
#include <cstdint>

typedef unsigned short u16;
typedef __attribute__((ext_vector_type(8))) short s16x8;
typedef __attribute__((ext_vector_type(4))) float f32x4;

#define NTOK 4096
#define DH   64
#define DM   1024
#define NH   16

static __device__ __forceinline__ float b2f(u16 u){ return __uint_as_float(((unsigned)u)<<16); }
static __device__ __forceinline__ u16 f2b(float f){
  unsigned u = __float_as_uint(f);
  return (u16)((u + 0x7FFFu + ((u>>16)&1u)) >> 16);   // RNE
}

static __device__ __forceinline__ void gload_lds16(const void* g, void* l) {
  __builtin_amdgcn_global_load_lds(
      (const __attribute__((address_space(1))) unsigned*)(uintptr_t)g,
      (__attribute__((address_space(3))) unsigned*)(uintptr_t)l, 16, 0, 0);
}

static __device__ __forceinline__ s16x8 ld8(const u16* p){ return *(const s16x8*)(const void*)p; }

// ---------------- convert fp32 -> bf16 (flat) ----------------
__global__ __launch_bounds__(256) void k_cvt(const float* __restrict__ in, u16* __restrict__ out, long n4) {
  long i = (long)blockIdx.x*blockDim.x + threadIdx.x;
  const long st = (long)gridDim.x*blockDim.x;
  for (; i < n4; i += st) {
    const float4 v = ((const float4*)in)[i];
    ushort4 o; o.x=f2b(v.x); o.y=f2b(v.y); o.z=f2b(v.z); o.w=f2b(v.w);
    ((ushort4*)out)[i] = o;
  }
}

// ---------------- convert+transpose: f32 [R][C] -> bf16 [C][R] ----------------
__global__ __launch_bounds__(256) void k_cvt_t(const float* __restrict__ in, u16* __restrict__ out, int R, int C) {
  __shared__ float tile[64][65];
  const int tc = blockIdx.x, tr = blockIdx.y;
  const int t = threadIdx.x, cx = t & 63, ry = t >> 6;
  #pragma unroll
  for (int p = 0; p < 16; ++p) {
    const int row = p*4 + ry;
    tile[row][cx] = in[(long)(tr*64 + row)*C + tc*64 + cx];
  }
  __syncthreads();
  #pragma unroll
  for (int p = 0; p < 16; ++p) {
    const int orow = p*4 + ry;
    out[(long)(tc*64 + orow)*R + tr*64 + cx] = f2b(tile[cx][orow]);
  }
}

// ---------------- landmark means of X (fp32, exact path for pinv) ----------------
__global__ __launch_bounds__(256) void k_xlmean(const float* __restrict__ hs, float* __restrict__ Xl) {
  const int row = blockIdx.x;             // b*64 + lm
  const int b = row >> 6, lm = row & 63;
  const int d = blockIdx.y*256 + threadIdx.x;
  const float* p = hs + ((long)b*NTOK + lm*64)*DM + d;
  float s = 0.f;
  #pragma unroll 16
  for (int i = 0; i < 64; ++i) s += p[(long)i*DM];
  Xl[(long)row*DM + d] = s * (1.0f/64.0f);
}

// ---------------- fp32 projection, K-split: psum[z][row][col] partials ----------------
__global__ __launch_bounds__(256) void k_lproj2(const float* __restrict__ Xl, const float* __restrict__ Wqkv,
                                                float* __restrict__ psum) {
  __shared__ __align__(16) float Xs[32][68];
  const int t = threadIdx.x;
  const int wcol = blockIdx.x*256 + t;    // 0..2047
  const int r0 = blockIdx.y*32;
  const int kbase = blockIdx.z*128;
  float acc[32];
  #pragma unroll
  for (int r = 0; r < 32; ++r) acc[r] = 0.f;
  for (int k0 = kbase; k0 < kbase + 128; k0 += 64) {
    __syncthreads();
    for (int idx = t; idx < 2048; idx += 256)
      Xs[idx>>6][idx&63] = Xl[(long)(r0 + (idx>>6))*DM + k0 + (idx&63)];
    __syncthreads();
    for (int kk = 0; kk < 64; kk += 4) {
      f32x4 wv;
      #pragma unroll
      for (int j = 0; j < 4; ++j) wv[j] = Wqkv[(long)(k0+kk+j)*3072 + wcol];
      #pragma unroll
      for (int r = 0; r < 32; ++r) {
        const f32x4 xv = *(const f32x4*)&Xs[r][kk];
        acc[r] += xv[0]*wv[0] + xv[1]*wv[1] + xv[2]*wv[2] + xv[3]*wv[3];
      }
    }
  }
  float* po = psum + ((long)blockIdx.z*256 + r0)*2048 + wcol;
  #pragma unroll
  for (int r = 0; r < 32; ++r) po[(long)r*2048] = acc[r];
}

// ---------------- reduce K-slices + bias + scale -> qlf/klf/qlb/klb ----------------
__global__ __launch_bounds__(256) void k_lreduce(const float* __restrict__ psum, const float* __restrict__ bqkv,
                                                 float* __restrict__ qlf, float* __restrict__ klf,
                                                 u16* __restrict__ qlb, u16* __restrict__ klb) {
  const long idx = (long)blockIdx.x*256 + threadIdx.x;   // 0..524287
  const int row = (int)(idx >> 11), col = (int)(idx & 2047);
  float s = 0.f;
  #pragma unroll
  for (int z = 0; z < 8; ++z) s += psum[((long)z*256 + row)*2048 + col];
  const int isq = (col < 1024) ? 1 : 0;
  float val = s + bqkv[col];
  if (isq) val *= 0.125f;
  const int b = row >> 6, lm = row & 63;
  const int c2 = col & 1023, h = c2 >> 6, dh = c2 & 63;
  const long o = (((long)b*NH + h)*64 + lm)*64 + dh;
  if (isq) { qlf[o] = val; qlb[o] = f2b(val); }
  else     { klf[o] = val; klb[o] = f2b(val); }
}

// ---------------- GEMM 256x256, BK=32, 8 waves, 4-deep LDS ring, counted vmcnt ----------------
// A[M,1024] bf16 row-major, Bt[N,1024] bf16 row-major (= B^T). K fixed = 1024 (32 K-tiles).
// EPI=0: qkv epilogue; EPI=1: fp32 out + bias (N=1024).
template<int EPI>
__global__ __launch_bounds__(512, 2) void k_gemm256(
    const u16* __restrict__ A, const u16* __restrict__ Bt, const float* __restrict__ bias,
    int N, float* __restrict__ outF, u16* __restrict__ outQ, u16* __restrict__ outK, u16* __restrict__ outV)
{
  // ring: 4 x 32KB; per buffer: A tile [256][32] at +0 (16KB), B tile [256][32] at +16384
  __shared__ __align__(16) u16 lds[4*16384];
  const int K = 1024;
  const int t = threadIdx.x;
  const int lane = t & 63;
  const int wid = t >> 6;
  const int c = lane & 15, g = lane >> 4;
  const int wm = wid >> 2, wn = wid & 3;
  const long arow0 = (long)blockIdx.x * 256;
  const long brow0 = (long)blockIdx.y * 256;
  char* ldsb = (char*)lds;

  // staging: thread t stages row (t>>2) of a 128-row half, 16B chunk (t&3)
  const int srow = t >> 2, schunk = t & 3;
  const u16* gA0 = A  + (arow0 + srow)*K       + schunk*8;
  const u16* gA1 = A  + (arow0 + 128 + srow)*K + schunk*8;
  const u16* gB0 = Bt + (brow0 + srow)*K       + schunk*8;
  const u16* gB1 = Bt + (brow0 + 128 + srow)*K + schunk*8;
  const int dstoff = t*16;

#define STAGE_A(kt) { char* bse = ldsb + ((kt)&3)*32768; \
    gload_lds16(gA0 + (kt)*32, bse + dstoff); \
    gload_lds16(gA1 + (kt)*32, bse + 8192 + dstoff); }
#define STAGE_B(kt) { char* bse = ldsb + ((kt)&3)*32768 + 16384; \
    gload_lds16(gB0 + (kt)*32, bse + dstoff); \
    gload_lds16(gB1 + (kt)*32, bse + 8192 + dstoff); }

  // fragment LDS byte offsets (within a buffer)
  int aoff[2][4], boff[4];
  #pragma unroll
  for (int mi = 0; mi < 4; ++mi) {
    aoff[0][mi] = (0*128 + wm*64 + mi*16 + c)*64 + g*16;
    aoff[1][mi] = (1*128 + wm*64 + mi*16 + c)*64 + g*16;
    boff[mi]    = 16384 + (wn*64 + mi*16 + c)*64 + g*16;
  }

  f32x4 acc0[4][4] = {};
  f32x4 acc1[4][4] = {};

  // prologue: stage K-tiles 0,1,2 (12 loads); wait for tile 0 (keep 8 in flight)
  STAGE_A(0); STAGE_B(0); STAGE_A(1); STAGE_B(1); STAGE_A(2); STAGE_B(2);
  asm volatile("s_waitcnt vmcnt(8)" ::: "memory");
  __builtin_amdgcn_s_barrier();

  for (int kt = 0; kt < 32; ++kt) {
    char* buf = ldsb + (kt&3)*32768;
    // ---- phase 0: C rows 0-127 of tile ----
    if (kt + 3 < 32) STAGE_A(kt+3)
    s16x8 af[4], bfr[4];
    #pragma unroll
    for (int mi = 0; mi < 4; ++mi) af[mi]  = *(const s16x8*)(buf + aoff[0][mi]);
    #pragma unroll
    for (int ni = 0; ni < 4; ++ni) bfr[ni] = *(const s16x8*)(buf + boff[ni]);
    asm volatile("s_waitcnt lgkmcnt(0)" ::: "memory");
    __builtin_amdgcn_sched_barrier(0);
    __builtin_amdgcn_s_setprio(1);
    #pragma unroll
    for (int mi = 0; mi < 4; ++mi)
      #pragma unroll
      for (int ni = 0; ni < 4; ++ni)
        acc0[mi][ni] = __builtin_amdgcn_mfma_f32_16x16x32_bf16(af[mi], bfr[ni], acc0[mi][ni], 0, 0, 0);
    __builtin_amdgcn_s_setprio(0);
    __builtin_amdgcn_s_barrier();
    // ---- phase 1: C rows 128-255 (B frags reused from phase 0) ----
    if (kt + 3 < 32) STAGE_B(kt+3)
    s16x8 af2[4];
    #pragma unroll
    for (int mi = 0; mi < 4; ++mi) af2[mi] = *(const s16x8*)(buf + aoff[1][mi]);
    asm volatile("s_waitcnt lgkmcnt(0)" ::: "memory");
    __builtin_amdgcn_sched_barrier(0);
    __builtin_amdgcn_s_setprio(1);
    #pragma unroll
    for (int mi = 0; mi < 4; ++mi)
      #pragma unroll
      for (int ni = 0; ni < 4; ++ni)
        acc1[mi][ni] = __builtin_amdgcn_mfma_f32_16x16x32_bf16(af2[mi], bfr[ni], acc1[mi][ni], 0, 0, 0);
    __builtin_amdgcn_s_setprio(0);
    // K-tile boundary: retire tile kt+1's loads; keep kt+2/kt+3 in flight (per-wave FIFO)
    if (kt <= 28)      { asm volatile("s_waitcnt vmcnt(8)" ::: "memory"); }
    else if (kt == 29) { asm volatile("s_waitcnt vmcnt(4)" ::: "memory"); }
    else if (kt == 30) { asm volatile("s_waitcnt vmcnt(0)" ::: "memory"); }
    __builtin_amdgcn_s_barrier();
  }
#undef STAGE_A
#undef STAGE_B

  if (EPI == 0) {
    const int tensor = (int)(brow0 >> 10);
    u16* dst = (tensor == 0) ? outQ : (tensor == 1) ? outK : outV;
    const float mul = (tensor == 0) ? 0.125f : 1.0f;
    #pragma unroll
    for (int ph = 0; ph < 2; ++ph)
      #pragma unroll
      for (int mi = 0; mi < 4; ++mi) {
        const int rowb = ph*128 + wm*64 + mi*16 + g*4;
        #pragma unroll
        for (int ni = 0; ni < 4; ++ni) {
          const long gcol = brow0 + wn*64 + ni*16 + c;
          const int c2 = (int)(gcol & 1023);
          const int head = c2 >> 6, dh = c2 & 63;
          const float bv = bias[gcol];
          const f32x4 a = ph ? acc1[mi][ni] : acc0[mi][ni];
          #pragma unroll
          for (int r = 0; r < 4; ++r) {
            const long grow = arow0 + rowb + r;
            const int b = (int)(grow >> 12), tok = (int)(grow & 4095);
            dst[(((long)b*NH + head)*NTOK + tok)*DH + dh] = f2b((a[r] + bv)*mul);
          }
        }
      }
  } else {
    #pragma unroll
    for (int ph = 0; ph < 2; ++ph)
      #pragma unroll
      for (int mi = 0; mi < 4; ++mi) {
        const int rowb = ph*128 + wm*64 + mi*16 + g*4;
        #pragma unroll
        for (int ni = 0; ni < 4; ++ni) {
          const long gcol = brow0 + wn*64 + ni*16 + c;
          const float bv = bias[gcol];
          const f32x4 a = ph ? acc1[mi][ni] : acc0[mi][ni];
          #pragma unroll
          for (int r = 0; r < 4; ++r) {
            const long grow = arow0 + rowb + r;
            outF[grow*N + gcol] = a[r] + bv;
          }
        }
      }
  }
}

// ---------------- v transpose: [bh][tok][dh] -> [bh][dh][tok] ----------------
__global__ __launch_bounds__(256) void k_vtrans(const u16* __restrict__ v, u16* __restrict__ vt) {
  __shared__ u16 tile[64][65];
  const int bh = blockIdx.x >> 6, tt = blockIdx.x & 63;
  const int t = threadIdx.x, cx = t & 63, ry = t >> 6;
  const u16* vp = v + ((long)bh*NTOK + tt*64)*DH;
  #pragma unroll
  for (int p = 0; p < 16; ++p) { const int row = p*4 + ry; tile[row][cx] = vp[row*DH + cx]; }
  __syncthreads();
  u16* op = vt + (long)bh*DH*NTOK + tt*64;
  #pragma unroll
  for (int p = 0; p < 16; ++p) { const int orow = p*4 + ry; op[(long)orow*NTOK + cx] = tile[cx][orow]; }
}

// ---------------- fp32 LDS 64x64 matmul helpers, 512 threads (8 cols/thread) ----------------
#define PST 68
static __device__ __forceinline__ void mm_nn8(const float* A, const float* B, float* C, int t) {
  const int lane = t & 63, j0 = (t >> 6) << 3;
  float acc[8];
  #pragma unroll
  for (int j = 0; j < 8; ++j) acc[j] = 0.f;
  for (int k = 0; k < 64; k += 4) {
    const f32x4 a4 = *(const f32x4*)&A[lane*PST + k];
    #pragma unroll
    for (int dk = 0; dk < 4; ++dk) {
      const float a = a4[dk];
      const float* br = &B[(k + dk)*PST + j0];
      const f32x4 b0 = *(const f32x4*)(br);
      const f32x4 b1 = *(const f32x4*)(br + 4);
      #pragma unroll
      for (int qq = 0; qq < 4; ++qq) { acc[qq] += a*b0[qq]; acc[4+qq] += a*b1[qq]; }
    }
  }
  #pragma unroll
  for (int j = 0; j < 8; ++j) C[lane*PST + j0 + j] = acc[j];
}
static __device__ __forceinline__ void mm_nt8(const float* A, const float* B, float* C, int t) {
  const int lane = t & 63, j0 = (t >> 6) << 3;
  float acc[8];
  #pragma unroll
  for (int j = 0; j < 8; ++j) acc[j] = 0.f;
  for (int k = 0; k < 64; k += 4) {
    const f32x4 a4 = *(const f32x4*)&A[lane*PST + k];
    #pragma unroll
    for (int jj = 0; jj < 8; ++jj) {
      const f32x4 b4 = *(const f32x4*)&B[(j0 + jj)*PST + k];
      acc[jj] += a4[0]*b4[0] + a4[1]*b4[1] + a4[2]*b4[2] + a4[3]*b4[3];
    }
  }
  #pragma unroll
  for (int j = 0; j < 8; ++j) C[lane*PST + j0 + j] = acc[j];
}

// ---------------- sim2 + softmax + Newton-Schulz pinv (all fp32, 512 thr) ----------------
__global__ __launch_bounds__(512) void k_pinv(const float* __restrict__ qlf, const float* __restrict__ klf,
                                              float* __restrict__ a2inv) {
  __shared__ __align__(16) float Xb[64*PST];
  __shared__ __align__(16) float Vb[64*PST];
  __shared__ __align__(16) float T1[64*PST];
  __shared__ __align__(16) float T2[64*PST];
  __shared__ __align__(16) float T3[64*PST];
  const int bh = blockIdx.x, t = threadIdx.x;
  const float* ql = qlf + (long)bh*4096;
  const float* kl = klf + (long)bh*4096;
  for (int i = t; i < 4096; i += 512) { T1[(i>>6)*PST + (i&63)] = ql[i]; T2[(i>>6)*PST + (i&63)] = kl[i]; }
  __syncthreads();
  mm_nt8(T1, T2, Xb, t);          // sim2 = q_l @ k_l^T
  __syncthreads();
  if (t < 64) {                   // row softmax (precise exp on the chaotic path)
    float mx = -1e30f;
    for (int j = 0; j < 64; ++j) mx = fmaxf(mx, Xb[t*PST + j]);
    float s = 0.f;
    for (int j = 0; j < 64; ++j) { const float e = expf(Xb[t*PST + j] - mx); Xb[t*PST + j] = e; s += e; }
    const float inv = 1.0f/s;
    for (int j = 0; j < 64; ++j) Xb[t*PST + j] *= inv;
  }
  __syncthreads();
  for (int i = t; i < 4096; i += 512) { const int r = i>>6, cc = i&63; Vb[r*PST+cc] = Xb[r*PST+cc]; }
  __syncthreads();
  for (int it = 0; it < 6; ++it) {
    mm_nn8(Xb, Vb, T1, t);  __syncthreads();                 // KV
    for (int i = t; i < 4096; i += 512) { const int r=i>>6, cc=i&63; T2[r*PST+cc] = (r==cc?7.0f:0.0f) - T1[r*PST+cc]; }
    __syncthreads();
    mm_nn8(T1, T2, T3, t);  __syncthreads();                 // KV@(7I-KV)
    for (int i = t; i < 4096; i += 512) { const int r=i>>6, cc=i&63; T2[r*PST+cc] = (r==cc?15.0f:0.0f) - T3[r*PST+cc]; }
    __syncthreads();
    mm_nn8(T1, T2, T3, t);  __syncthreads();                 // KV@(15I-...)
    for (int i = t; i < 4096; i += 512) { const int r=i>>6, cc=i&63; T2[r*PST+cc] = (r==cc?13.0f:0.0f) - T3[r*PST+cc]; }
    __syncthreads();
    mm_nn8(Vb, T2, T3, t);  __syncthreads();                 // V@(13I-...)
    for (int i = t; i < 4096; i += 512) { const int r=i>>6, cc=i&63; Vb[r*PST+cc] = 0.25f*T3[r*PST+cc]; }
    __syncthreads();
  }
  for (int i = t; i < 4096; i += 512) a2inv[(long)bh*4096 + i] = Vb[(i>>6)*PST + (i&63)];
}

// ---------------- attn3 @ v partials: 4 blocks per (b,h), 1024 tokens each ----------------
__global__ __launch_bounds__(256) void k_attn3v_p(const u16* __restrict__ qlb, const u16* __restrict__ kk,
                                                  const u16* __restrict__ vt,
                                                  float* __restrict__ zp, float* __restrict__ sp) {
  __shared__ __align__(16) float Zl[4][64][64];
  __shared__ float Sl[4][64];
  __shared__ __align__(16) u16 Pl[4][64][40];   // rows padded to 80B (32 cols used)
  const int bh = blockIdx.x >> 2, qt = blockIdx.x & 3;
  const int t = threadIdx.x, w = t >> 6, lane = t & 63;
  const int c = lane & 15, g = lane >> 4;

  s16x8 aq[4][2];
  const u16* qlp = qlb + (long)bh*4096;
  #pragma unroll
  for (int mi = 0; mi < 4; ++mi)
    #pragma unroll
    for (int ks = 0; ks < 2; ++ks)
      aq[mi][ks] = ld8(qlp + (mi*16 + c)*64 + ks*32 + g*8);

  f32x4 zacc[4][4] = {};
  float sl[4][4] = {};
  const u16* kp = kk + (long)bh*NTOK*DH;
  const u16* vp = vt + (long)bh*DH*NTOK;
  char* pbase = (char*)&Pl[w][0][0];
  const int tok00 = qt*1024 + w*256;

  for (int it = 0; it < 8; ++it) {
    const int t0 = tok00 + it*32;
    f32x4 sacc[4][2] = {};
    s16x8 kb[2][2];
    #pragma unroll
    for (int cg = 0; cg < 2; ++cg)
      #pragma unroll
      for (int ks = 0; ks < 2; ++ks)
        kb[cg][ks] = ld8(kp + (long)(t0 + cg*16 + c)*64 + ks*32 + g*8);
    #pragma unroll
    for (int cg = 0; cg < 2; ++cg)
      #pragma unroll
      for (int ks = 0; ks < 2; ++ks)
        #pragma unroll
        for (int mi = 0; mi < 4; ++mi)
          sacc[mi][cg] = __builtin_amdgcn_mfma_f32_16x16x32_bf16(aq[mi][ks], kb[cg][ks], sacc[mi][cg], 0, 0, 0);
    #pragma unroll
    for (int mi = 0; mi < 4; ++mi)
      #pragma unroll
      for (int r = 0; r < 4; ++r) {
        const int row = mi*16 + g*4 + r;
        const float p0 = __expf(sacc[mi][0][r]);
        const float p1 = __expf(sacc[mi][1][r]);
        sl[mi][r] += p0 + p1;
        char* base = pbase + row*80;
        *(u16*)(base + c*2)      = f2b(p0);
        *(u16*)(base + 32 + c*2) = f2b(p1);
      }
    s16x8 pa[4];
    #pragma unroll
    for (int mi = 0; mi < 4; ++mi) pa[mi] = *(const s16x8*)(pbase + (mi*16 + c)*80 + g*16);
    #pragma unroll
    for (int ni = 0; ni < 4; ++ni) {
      const s16x8 vb = ld8(vp + (long)(ni*16 + c)*NTOK + t0 + g*8);
      #pragma unroll
      for (int mi = 0; mi < 4; ++mi)
        zacc[mi][ni] = __builtin_amdgcn_mfma_f32_16x16x32_bf16(pa[mi], vb, zacc[mi][ni], 0, 0, 0);
    }
  }
  #pragma unroll
  for (int mi = 0; mi < 4; ++mi)
    #pragma unroll
    for (int r = 0; r < 4; ++r) {
      float s = sl[mi][r];
      s += __shfl_xor(s, 1); s += __shfl_xor(s, 2); s += __shfl_xor(s, 4); s += __shfl_xor(s, 8);
      sl[mi][r] = s;
    }
  #pragma unroll
  for (int mi = 0; mi < 4; ++mi)
    #pragma unroll
    for (int ni = 0; ni < 4; ++ni)
      #pragma unroll
      for (int r = 0; r < 4; ++r)
        Zl[w][mi*16 + g*4 + r][ni*16 + c] = zacc[mi][ni][r];
  if (c == 0)
    #pragma unroll
    for (int mi = 0; mi < 4; ++mi)
      #pragma unroll
      for (int r = 0; r < 4; ++r)
        Sl[w][mi*16 + g*4 + r] = sl[mi][r];
  __syncthreads();
  float* zpp = zp + (long)blockIdx.x*4096;
  for (int i = t; i < 4096; i += 256) {
    const int row = i >> 6, dh = i & 63;
    zpp[i] = Zl[0][row][dh] + Zl[1][row][dh] + Zl[2][row][dh] + Zl[3][row][dh];
  }
  if (t < 64) sp[(long)blockIdx.x*64 + t] = Sl[0][t] + Sl[1][t] + Sl[2][t] + Sl[3][t];
}

// ---------------- reduce attn3v partials -> z ----------------
__global__ __launch_bounds__(256) void k_zred(const float* __restrict__ zp, const float* __restrict__ sp,
                                              float* __restrict__ z) {
  const int bh = blockIdx.x, t = threadIdx.x;
  for (int i = t; i < 4096; i += 256) {
    const int row = i >> 6;
    float zs = 0.f, ss = 0.f;
    #pragma unroll
    for (int qt = 0; qt < 4; ++qt) {
      zs += zp[((long)(bh*4 + qt))*4096 + i];
      ss += sp[(long)(bh*4 + qt)*64 + row];
    }
    z[(long)bh*4096 + i] = zs / ss;
  }
}

// ---------------- W2^T = (attn2inv @ z)^T  (bf16 out, [dh][lm], 512 thr) ----------------
__global__ __launch_bounds__(512) void k_w2(const float* __restrict__ a2inv, const float* __restrict__ z,
                                            u16* __restrict__ w2t) {
  __shared__ __align__(16) float Ai[64*PST];
  __shared__ __align__(16) float Zi[64*PST];
  __shared__ __align__(16) float Ci[64*PST];
  const int bh = blockIdx.x, t = threadIdx.x;
  for (int i = t; i < 4096; i += 512) {
    Ai[(i>>6)*PST + (i&63)] = a2inv[(long)bh*4096 + i];
    Zi[(i>>6)*PST + (i&63)] = z[(long)bh*4096 + i];
  }
  __syncthreads();
  mm_nn8(Ai, Zi, Ci, t);
  __syncthreads();
  for (int i = t; i < 4096; i += 512) { const int r = i>>6, cc = i&63; w2t[(long)bh*4096 + cc*64 + r] = f2b(Ci[r*PST + cc]); }
}

// ---------------- out_h = softmax(q @ k_l^T) @ W2, fused, writes attnout bf16 ----------------
#define P1ST 144   /* bytes per P row */
__global__ __launch_bounds__(256) void k_attn1(const u16* __restrict__ q, const u16* __restrict__ klb,
                                               const u16* __restrict__ w2t, u16* __restrict__ ao) {
  __shared__ __align__(16) u16 Pl[4][64][72];
  const int bx = blockIdx.x, bh = bx >> 4, tt = bx & 15;
  const int b = bh >> 4, h = bh & 15;
  const int t = threadIdx.x, w = t >> 6, lane = t & 63;
  const int c = lane & 15, g = lane >> 4;
  const int tok0 = tt*256 + w*64;
  const u16* qp  = q + ((long)bh*NTOK + tok0)*DH;
  const u16* klp = klb + (long)bh*4096;
  const u16* wp  = w2t + (long)bh*4096;
  char* pbase = (char*)&Pl[w][0][0];

  s16x8 aq[4][2], kb[4][2], wb[4][2];
  #pragma unroll
  for (int i = 0; i < 4; ++i)
    #pragma unroll
    for (int ks = 0; ks < 2; ++ks) {
      aq[i][ks] = ld8(qp + (long)(i*16 + c)*DH + ks*32 + g*8);
      kb[i][ks] = ld8(klp + (i*16 + c)*64 + ks*32 + g*8);
      wb[i][ks] = ld8(wp  + (i*16 + c)*64 + ks*32 + g*8);
    }
  f32x4 sacc[4][4] = {};
  #pragma unroll
  for (int ks = 0; ks < 2; ++ks)
    #pragma unroll
    for (int mi = 0; mi < 4; ++mi)
      #pragma unroll
      for (int ni = 0; ni < 4; ++ni)
        sacc[mi][ni] = __builtin_amdgcn_mfma_f32_16x16x32_bf16(aq[mi][ks], kb[ni][ks], sacc[mi][ni], 0, 0, 0);

  float rs[4][4];
  #pragma unroll
  for (int mi = 0; mi < 4; ++mi)
    #pragma unroll
    for (int r = 0; r < 4; ++r) {
      const int row = mi*16 + g*4 + r;
      char* base = pbase + row*P1ST;
      float ssum = 0.f;
      #pragma unroll
      for (int ni = 0; ni < 4; ++ni) {
        const float p = __expf(sacc[mi][ni][r]);
        ssum += p;
        *(u16*)(base + (ni*16 + c)*2) = f2b(p);
      }
      ssum += __shfl_xor(ssum, 1); ssum += __shfl_xor(ssum, 2);
      ssum += __shfl_xor(ssum, 4); ssum += __shfl_xor(ssum, 8);
      rs[mi][r] = ssum;
    }
  __builtin_amdgcn_s_barrier();   // intra-wave store->read ordering
  s16x8 pa[4][2];
  #pragma unroll
  for (int mi = 0; mi < 4; ++mi)
    #pragma unroll
    for (int ks = 0; ks < 2; ++ks)
      pa[mi][ks] = *(const s16x8*)(pbase + (mi*16 + c)*P1ST + ks*64 + g*16);
  f32x4 oacc[4][4] = {};
  #pragma unroll
  for (int ks = 0; ks < 2; ++ks)
    #pragma unroll
    for (int mi = 0; mi < 4; ++mi)
      #pragma unroll
      for (int ni = 0; ni < 4; ++ni)
        oacc[mi][ni] = __builtin_amdgcn_mfma_f32_16x16x32_bf16(pa[mi][ks], wb[ni][ks], oacc[mi][ni], 0, 0, 0);

  u16* op = ao + (long)b*NTOK*DM + (long)h*64;
  #pragma unroll
  for (int mi = 0; mi < 4; ++mi)
    #pragma unroll
    for (int r = 0; r < 4; ++r) {
      const int tok = tok0 + mi*16 + g*4 + r;
      const float inv = 1.0f / rs[mi][r];
      #pragma unroll
      for (int ni = 0; ni < 4; ++ni)
        op[(long)tok*DM + ni*16 + c] = f2b(oacc[mi][ni][r] * inv);
    }
}

extern "C" void kernel_launch(void* const* d_in, const int* in_sizes, int n_in,
                              void* d_out, int out_size, void* d_ws, size_t ws_size,
                              hipStream_t stream) {
  const float* hs   = (const float*)d_in[0];
  const float* Wqkv = (const float*)d_in[1];
  const float* bqkv = (const float*)d_in[2];
  const float* Wout = (const float*)d_in[3];
  const float* bout = (const float*)d_in[4];
  float* out = (float*)d_out;
  char* w = (char*)d_ws;

  u16*  Xb    = (u16*)(w);                 // 32MB; free after QKV gemm
  float* zp   = (float*)(w);               // aliases Xb: written by attn3v_p (after gemm0)
  float* sp   = (float*)(w + 4194304L);    // within Xb region
  u16*  WqkvT = (u16*)(w + 33554432L);
  u16*  WoutT = (u16*)(w + 39845888L);
  u16*  q     = (u16*)(w + 41943040L);
  float* psum = (float*)(w + 41943040L);   // aliases q: consumed by k_lreduce before gemm writes q
  u16*  k     = (u16*)(w + 75497472L);
  u16*  v     = (u16*)(w + 109051904L);
  u16*  vt    = (u16*)(w + 142606336L);
  float* Xl   = (float*)(w + 142606336L);  // aliases vt: consumed before k_vtrans writes
  float* qlf  = (float*)(w + 176160768L);
  float* klf  = (float*)(w + 177209344L);
  u16*  qlb   = (u16*)(w + 178257920L);
  u16*  klb   = (u16*)(w + 178782208L);
  float* a2i  = (float*)(w + 179306496L);
  float* z    = (float*)(w + 180355072L);
  u16*  w2t   = (u16*)(w + 181403648L);
  u16*  ao    = (u16*)(w + 181927936L);

  k_cvt<<<2048, 256, 0, stream>>>(hs, Xb, 4194304L);
  k_cvt_t<<<dim3(48,16), 256, 0, stream>>>(Wqkv, WqkvT, 1024, 3072);
  k_cvt_t<<<dim3(16,16), 256, 0, stream>>>(Wout, WoutT, 1024, 1024);
  k_xlmean<<<dim3(256,4), 256, 0, stream>>>(hs, Xl);
  k_lproj2<<<dim3(8,8,8), 256, 0, stream>>>(Xl, Wqkv, psum);
  k_lreduce<<<2048, 256, 0, stream>>>(psum, bqkv, qlf, klf, qlb, klb);
  k_gemm256<0><<<dim3(64,12), 512, 0, stream>>>(Xb, WqkvT, bqkv, 3072, nullptr, q, k, v);
  k_vtrans<<<4096, 256, 0, stream>>>(v, vt);
  k_pinv<<<64, 512, 0, stream>>>(qlf, klf, a2i);
  k_attn3v_p<<<256, 256, 0, stream>>>(qlb, k, vt, zp, sp);
  k_zred<<<64, 256, 0, stream>>>(zp, sp, z);
  k_w2<<<64, 512, 0, stream>>>(a2i, z, w2t);
  k_attn1<<<1024, 256, 0, stream>>>(q, klb, w2t, ao);
  k_gemm256<1><<<dim3(64,4), 512, 0, stream>>>(ao, WoutT, bout, 1024, out, nullptr, nullptr, nullptr);
}

// Round 5
// 374.931 us; speedup vs baseline: 1.7259x; 1.0292x over previous
//
#include <hip/hip_runtime.h>
#include <cstdint>

typedef unsigned short u16;
typedef __attribute__((ext_vector_type(8))) short s16x8;
typedef __attribute__((ext_vector_type(4))) float f32x4;

#define NTOK 4096
#define DH   64
#define DM   1024
#define NH   16

static __device__ __forceinline__ float b2f(u16 u){ return __uint_as_float(((unsigned)u)<<16); }
static __device__ __forceinline__ u16 f2b(float f){
  unsigned u = __float_as_uint(f);
  return (u16)((u + 0x7FFFu + ((u>>16)&1u)) >> 16);   // RNE
}

static __device__ __forceinline__ void gload_lds16(const void* g, void* l) {
  __builtin_amdgcn_global_load_lds(
      (const __attribute__((address_space(1))) unsigned*)(uintptr_t)g,
      (__attribute__((address_space(3))) unsigned*)(uintptr_t)l, 16, 0, 0);
}

static __device__ __forceinline__ s16x8 ld8(const u16* p){ return *(const s16x8*)(const void*)p; }

// ---------------- convert fp32 -> bf16 (flat) ----------------
__global__ __launch_bounds__(256) void k_cvt(const float* __restrict__ in, u16* __restrict__ out, long n4) {
  long i = (long)blockIdx.x*blockDim.x + threadIdx.x;
  const long st = (long)gridDim.x*blockDim.x;
  for (; i < n4; i += st) {
    const float4 v = ((const float4*)in)[i];
    ushort4 o; o.x=f2b(v.x); o.y=f2b(v.y); o.z=f2b(v.z); o.w=f2b(v.w);
    ((ushort4*)out)[i] = o;
  }
}

// ---------------- convert+transpose: f32 [R][C] -> bf16 [C][R] ----------------
__global__ __launch_bounds__(256) void k_cvt_t(const float* __restrict__ in, u16* __restrict__ out, int R, int C) {
  __shared__ float tile[64][65];
  const int tc = blockIdx.x, tr = blockIdx.y;
  const int t = threadIdx.x, cx = t & 63, ry = t >> 6;
  #pragma unroll
  for (int p = 0; p < 16; ++p) {
    const int row = p*4 + ry;
    tile[row][cx] = in[(long)(tr*64 + row)*C + tc*64 + cx];
  }
  __syncthreads();
  #pragma unroll
  for (int p = 0; p < 16; ++p) {
    const int orow = p*4 + ry;
    out[(long)(tc*64 + orow)*R + tr*64 + cx] = f2b(tile[cx][orow]);
  }
}

// ---------------- landmark means of X (fp32, exact path for pinv) ----------------
__global__ __launch_bounds__(256) void k_xlmean(const float* __restrict__ hs, float* __restrict__ Xl) {
  const int row = blockIdx.x;             // b*64 + lm
  const int b = row >> 6, lm = row & 63;
  const int d = blockIdx.y*256 + threadIdx.x;
  const float* p = hs + ((long)b*NTOK + lm*64)*DM + d;
  float s = 0.f;
  #pragma unroll 16
  for (int i = 0; i < 64; ++i) s += p[(long)i*DM];
  Xl[(long)row*DM + d] = s * (1.0f/64.0f);
}

// ---------------- fp32 projection, K-split: psum[z][row][col] partials ----------------
__global__ __launch_bounds__(256) void k_lproj2(const float* __restrict__ Xl, const float* __restrict__ Wqkv,
                                                float* __restrict__ psum) {
  __shared__ __align__(16) float Xs[32][68];
  const int t = threadIdx.x;
  const int wcol = blockIdx.x*256 + t;    // 0..2047
  const int r0 = blockIdx.y*32;
  const int kbase = blockIdx.z*128;
  float acc[32];
  #pragma unroll
  for (int r = 0; r < 32; ++r) acc[r] = 0.f;
  for (int k0 = kbase; k0 < kbase + 128; k0 += 64) {
    __syncthreads();
    for (int idx = t; idx < 2048; idx += 256)
      Xs[idx>>6][idx&63] = Xl[(long)(r0 + (idx>>6))*DM + k0 + (idx&63)];
    __syncthreads();
    for (int kk = 0; kk < 64; kk += 4) {
      f32x4 wv;
      #pragma unroll
      for (int j = 0; j < 4; ++j) wv[j] = Wqkv[(long)(k0+kk+j)*3072 + wcol];
      #pragma unroll
      for (int r = 0; r < 32; ++r) {
        const f32x4 xv = *(const f32x4*)&Xs[r][kk];
        acc[r] += xv[0]*wv[0] + xv[1]*wv[1] + xv[2]*wv[2] + xv[3]*wv[3];
      }
    }
  }
  float* po = psum + ((long)blockIdx.z*256 + r0)*2048 + wcol;
  #pragma unroll
  for (int r = 0; r < 32; ++r) po[(long)r*2048] = acc[r];
}

// ---------------- reduce K-slices + bias + scale -> qlf/klf/qlb/klb ----------------
__global__ __launch_bounds__(256) void k_lreduce(const float* __restrict__ psum, const float* __restrict__ bqkv,
                                                 float* __restrict__ qlf, float* __restrict__ klf,
                                                 u16* __restrict__ qlb, u16* __restrict__ klb) {
  const long idx = (long)blockIdx.x*256 + threadIdx.x;   // 0..524287
  const int row = (int)(idx >> 11), col = (int)(idx & 2047);
  float s = 0.f;
  #pragma unroll
  for (int z = 0; z < 8; ++z) s += psum[((long)z*256 + row)*2048 + col];
  const int isq = (col < 1024) ? 1 : 0;
  float val = s + bqkv[col];
  if (isq) val *= 0.125f;
  const int b = row >> 6, lm = row & 63;
  const int c2 = col & 1023, h = c2 >> 6, dh = c2 & 63;
  const long o = (((long)b*NH + h)*64 + lm)*64 + dh;
  if (isq) { qlf[o] = val; qlb[o] = f2b(val); }
  else     { klf[o] = val; klb[o] = f2b(val); }
}

// ---------------- GEMM 256x256, BK=32, 8 waves, 4-deep LDS ring, counted vmcnt ----------------
// LDS bank-conflict fix: chunk-XOR swizzle. LDS stays linear (global_load_lds needs it);
// the GLOBAL source chunk is pre-swizzled (ch ^ (row>>1)&3) and the ds_read offset uses
// g ^ (c>>1)&3  -> quarter-wave spreads over 8 bank-quads (2-way = free) instead of 2 (8-way).
// One barrier per K-tile: stages go to buf (kt+3)&3, reads to buf kt&3; reads drain at
// lgkmcnt(0) before the end-of-tile barrier, overwrite of buf[kt&3] starts at kt+1.
template<int EPI>
__global__ __launch_bounds__(512, 2) void k_gemm256(
    const u16* __restrict__ A, const u16* __restrict__ Bt, const float* __restrict__ bias,
    int N, float* __restrict__ outF, u16* __restrict__ outQ, u16* __restrict__ outK, u16* __restrict__ outV)
{
  // ring: 4 x 32KB; per buffer: A tile [256][32] at +0 (16KB), B tile [256][32] at +16384
  __shared__ __align__(16) u16 lds[4*16384];
  const int K = 1024;
  const int t = threadIdx.x;
  const int lane = t & 63;
  const int wid = t >> 6;
  const int c = lane & 15, g = lane >> 4;
  const int wm = wid >> 2, wn = wid & 3;
  const long arow0 = (long)blockIdx.x * 256;
  const long brow0 = (long)blockIdx.y * 256;
  char* ldsb = (char*)lds;

  // staging: thread t -> LDS row (t>>2), chunk (t&3); global chunk pre-swizzled
  const int srow = t >> 2;
  const int schunk = (t & 3) ^ ((srow >> 1) & 3);
  const u16* gA0 = A  + (arow0 + srow)*K       + schunk*8;
  const u16* gA1 = A  + (arow0 + 128 + srow)*K + schunk*8;
  const u16* gB0 = Bt + (brow0 + srow)*K       + schunk*8;
  const u16* gB1 = Bt + (brow0 + 128 + srow)*K + schunk*8;
  const int dstoff = t*16;

#define STAGE_A(kt) { char* bse = ldsb + ((kt)&3)*32768; \
    gload_lds16(gA0 + (kt)*32, bse + dstoff); \
    gload_lds16(gA1 + (kt)*32, bse + 8192 + dstoff); }
#define STAGE_B(kt) { char* bse = ldsb + ((kt)&3)*32768 + 16384; \
    gload_lds16(gB0 + (kt)*32, bse + dstoff); \
    gload_lds16(gB1 + (kt)*32, bse + 8192 + dstoff); }

  // fragment LDS byte offsets (within a buffer); read-side swizzle matches source swizzle
  const int gs = g ^ ((c >> 1) & 3);
  int aoff[2][4], boff[4];
  #pragma unroll
  for (int mi = 0; mi < 4; ++mi) {
    aoff[0][mi] = (0*128 + wm*64 + mi*16 + c)*64 + gs*16;
    aoff[1][mi] = (1*128 + wm*64 + mi*16 + c)*64 + gs*16;
    boff[mi]    = 16384 + (wn*64 + mi*16 + c)*64 + gs*16;
  }

  f32x4 acc0[4][4] = {};
  f32x4 acc1[4][4] = {};

  // prologue: stage K-tiles 0,1,2 (12 loads); wait for tile 0 (keep 8 in flight)
  STAGE_A(0); STAGE_B(0); STAGE_A(1); STAGE_B(1); STAGE_A(2); STAGE_B(2);
  asm volatile("s_waitcnt vmcnt(8)" ::: "memory");
  __builtin_amdgcn_s_barrier();

  for (int kt = 0; kt < 32; ++kt) {
    char* buf = ldsb + (kt&3)*32768;
    if (kt + 3 < 32) { STAGE_A(kt+3) STAGE_B(kt+3) }
    s16x8 af[4], af2[4], bfr[4];
    #pragma unroll
    for (int mi = 0; mi < 4; ++mi) af[mi]  = *(const s16x8*)(buf + aoff[0][mi]);
    #pragma unroll
    for (int ni = 0; ni < 4; ++ni) bfr[ni] = *(const s16x8*)(buf + boff[ni]);
    #pragma unroll
    for (int mi = 0; mi < 4; ++mi) af2[mi] = *(const s16x8*)(buf + aoff[1][mi]);
    asm volatile("s_waitcnt lgkmcnt(0)" ::: "memory");
    __builtin_amdgcn_sched_barrier(0);
    __builtin_amdgcn_s_setprio(1);
    #pragma unroll
    for (int mi = 0; mi < 4; ++mi)
      #pragma unroll
      for (int ni = 0; ni < 4; ++ni)
        acc0[mi][ni] = __builtin_amdgcn_mfma_f32_16x16x32_bf16(af[mi], bfr[ni], acc0[mi][ni], 0, 0, 0);
    #pragma unroll
    for (int mi = 0; mi < 4; ++mi)
      #pragma unroll
      for (int ni = 0; ni < 4; ++ni)
        acc1[mi][ni] = __builtin_amdgcn_mfma_f32_16x16x32_bf16(af2[mi], bfr[ni], acc1[mi][ni], 0, 0, 0);
    __builtin_amdgcn_s_setprio(0);
    // K-tile boundary: retire tile kt+1's loads; keep kt+2/kt+3 in flight (per-wave FIFO)
    if (kt <= 28)      { asm volatile("s_waitcnt vmcnt(8)" ::: "memory"); }
    else if (kt == 29) { asm volatile("s_waitcnt vmcnt(4)" ::: "memory"); }
    else if (kt == 30) { asm volatile("s_waitcnt vmcnt(0)" ::: "memory"); }
    __builtin_amdgcn_s_barrier();
  }
#undef STAGE_A
#undef STAGE_B

  if (EPI == 0) {
    const int tensor = (int)(brow0 >> 10);
    u16* dst = (tensor == 0) ? outQ : (tensor == 1) ? outK : outV;
    const float mul = (tensor == 0) ? 0.125f : 1.0f;
    #pragma unroll
    for (int ph = 0; ph < 2; ++ph)
      #pragma unroll
      for (int mi = 0; mi < 4; ++mi) {
        const int rowb = ph*128 + wm*64 + mi*16 + g*4;
        #pragma unroll
        for (int ni = 0; ni < 4; ++ni) {
          const long gcol = brow0 + wn*64 + ni*16 + c;
          const int c2 = (int)(gcol & 1023);
          const int head = c2 >> 6, dh = c2 & 63;
          const float bv = bias[gcol];
          const f32x4 a = ph ? acc1[mi][ni] : acc0[mi][ni];
          #pragma unroll
          for (int r = 0; r < 4; ++r) {
            const long grow = arow0 + rowb + r;
            const int b = (int)(grow >> 12), tok = (int)(grow & 4095);
            dst[(((long)b*NH + head)*NTOK + tok)*DH + dh] = f2b((a[r] + bv)*mul);
          }
        }
      }
  } else {
    #pragma unroll
    for (int ph = 0; ph < 2; ++ph)
      #pragma unroll
      for (int mi = 0; mi < 4; ++mi) {
        const int rowb = ph*128 + wm*64 + mi*16 + g*4;
        #pragma unroll
        for (int ni = 0; ni < 4; ++ni) {
          const long gcol = brow0 + wn*64 + ni*16 + c;
          const float bv = bias[gcol];
          const f32x4 a = ph ? acc1[mi][ni] : acc0[mi][ni];
          #pragma unroll
          for (int r = 0; r < 4; ++r) {
            const long grow = arow0 + rowb + r;
            outF[grow*N + gcol] = a[r] + bv;
          }
        }
      }
  }
}

// ---------------- v transpose: [bh][tok][dh] -> [bh][dh][tok] ----------------
__global__ __launch_bounds__(256) void k_vtrans(const u16* __restrict__ v, u16* __restrict__ vt) {
  __shared__ u16 tile[64][65];
  const int bh = blockIdx.x >> 6, tt = blockIdx.x & 63;
  const int t = threadIdx.x, cx = t & 63, ry = t >> 6;
  const u16* vp = v + ((long)bh*NTOK + tt*64)*DH;
  #pragma unroll
  for (int p = 0; p < 16; ++p) { const int row = p*4 + ry; tile[row][cx] = vp[row*DH + cx]; }
  __syncthreads();
  u16* op = vt + (long)bh*DH*NTOK + tt*64;
  #pragma unroll
  for (int p = 0; p < 16; ++p) { const int orow = p*4 + ry; op[(long)orow*NTOK + cx] = tile[cx][orow]; }
}

// ---------------- fp32 LDS 64x64 matmul helpers, 512 threads (8 cols/thread) ----------------
#define PST 68
static __device__ __forceinline__ void mm_nn8(const float* A, const float* B, float* C, int t) {
  const int lane = t & 63, j0 = (t >> 6) << 3;
  float acc[8];
  #pragma unroll
  for (int j = 0; j < 8; ++j) acc[j] = 0.f;
  for (int k = 0; k < 64; k += 4) {
    const f32x4 a4 = *(const f32x4*)&A[lane*PST + k];
    #pragma unroll
    for (int dk = 0; dk < 4; ++dk) {
      const float a = a4[dk];
      const float* br = &B[(k + dk)*PST + j0];
      const f32x4 b0 = *(const f32x4*)(br);
      const f32x4 b1 = *(const f32x4*)(br + 4);
      #pragma unroll
      for (int qq = 0; qq < 4; ++qq) { acc[qq] += a*b0[qq]; acc[4+qq] += a*b1[qq]; }
    }
  }
  #pragma unroll
  for (int j = 0; j < 8; ++j) C[lane*PST + j0 + j] = acc[j];
}
static __device__ __forceinline__ void mm_nt8(const float* A, const float* B, float* C, int t) {
  const int lane = t & 63, j0 = (t >> 6) << 3;
  float acc[8];
  #pragma unroll
  for (int j = 0; j < 8; ++j) acc[j] = 0.f;
  for (int k = 0; k < 64; k += 4) {
    const f32x4 a4 = *(const f32x4*)&A[lane*PST + k];
    #pragma unroll
    for (int jj = 0; jj < 8; ++jj) {
      const f32x4 b4 = *(const f32x4*)&B[(j0 + jj)*PST + k];
      acc[jj] += a4[0]*b4[0] + a4[1]*b4[1] + a4[2]*b4[2] + a4[3]*b4[3];
    }
  }
  #pragma unroll
  for (int j = 0; j < 8; ++j) C[lane*PST + j0 + j] = acc[j];
}

// ---------------- sim2 + softmax + Newton-Schulz pinv (all fp32, 512 thr) ----------------
__global__ __launch_bounds__(512) void k_pinv(const float* __restrict__ qlf, const float* __restrict__ klf,
                                              float* __restrict__ a2inv) {
  __shared__ __align__(16) float Xb[64*PST];
  __shared__ __align__(16) float Vb[64*PST];
  __shared__ __align__(16) float T1[64*PST];
  __shared__ __align__(16) float T2[64*PST];
  __shared__ __align__(16) float T3[64*PST];
  const int bh = blockIdx.x, t = threadIdx.x;
  const float* ql = qlf + (long)bh*4096;
  const float* kl = klf + (long)bh*4096;
  for (int i = t; i < 4096; i += 512) { T1[(i>>6)*PST + (i&63)] = ql[i]; T2[(i>>6)*PST + (i&63)] = kl[i]; }
  __syncthreads();
  mm_nt8(T1, T2, Xb, t);          // sim2 = q_l @ k_l^T
  __syncthreads();
  if (t < 64) {                   // row softmax (precise exp on the chaotic path)
    float mx = -1e30f;
    for (int j = 0; j < 64; ++j) mx = fmaxf(mx, Xb[t*PST + j]);
    float s = 0.f;
    for (int j = 0; j < 64; ++j) { const float e = expf(Xb[t*PST + j] - mx); Xb[t*PST + j] = e; s += e; }
    const float inv = 1.0f/s;
    for (int j = 0; j < 64; ++j) Xb[t*PST + j] *= inv;
  }
  __syncthreads();
  for (int i = t; i < 4096; i += 512) { const int r = i>>6, cc = i&63; Vb[r*PST+cc] = Xb[r*PST+cc]; }
  __syncthreads();
  for (int it = 0; it < 6; ++it) {
    mm_nn8(Xb, Vb, T1, t);  __syncthreads();                 // KV
    for (int i = t; i < 4096; i += 512) { const int r=i>>6, cc=i&63; T2[r*PST+cc] = (r==cc?7.0f:0.0f) - T1[r*PST+cc]; }
    __syncthreads();
    mm_nn8(T1, T2, T3, t);  __syncthreads();                 // KV@(7I-KV)
    for (int i = t; i < 4096; i += 512) { const int r=i>>6, cc=i&63; T2[r*PST+cc] = (r==cc?15.0f:0.0f) - T3[r*PST+cc]; }
    __syncthreads();
    mm_nn8(T1, T2, T3, t);  __syncthreads();                 // KV@(15I-...)
    for (int i = t; i < 4096; i += 512) { const int r=i>>6, cc=i&63; T2[r*PST+cc] = (r==cc?13.0f:0.0f) - T3[r*PST+cc]; }
    __syncthreads();
    mm_nn8(Vb, T2, T3, t);  __syncthreads();                 // V@(13I-...)
    for (int i = t; i < 4096; i += 512) { const int r=i>>6, cc=i&63; Vb[r*PST+cc] = 0.25f*T3[r*PST+cc]; }
    __syncthreads();
  }
  for (int i = t; i < 4096; i += 512) a2inv[(long)bh*4096 + i] = Vb[(i>>6)*PST + (i&63)];
}

// ---------------- attn3 @ v partials: 4 blocks per (b,h), 1024 tokens each ----------------
__global__ __launch_bounds__(256) void k_attn3v_p(const u16* __restrict__ qlb, const u16* __restrict__ kk,
                                                  const u16* __restrict__ vt,
                                                  float* __restrict__ zp, float* __restrict__ sp) {
  __shared__ __align__(16) float Zl[4][64][64];
  __shared__ float Sl[4][64];
  __shared__ __align__(16) u16 Pl[4][64][40];   // rows padded to 80B (32 cols used)
  const int bh = blockIdx.x >> 2, qt = blockIdx.x & 3;
  const int t = threadIdx.x, w = t >> 6, lane = t & 63;
  const int c = lane & 15, g = lane >> 4;

  s16x8 aq[4][2];
  const u16* qlp = qlb + (long)bh*4096;
  #pragma unroll
  for (int mi = 0; mi < 4; ++mi)
    #pragma unroll
    for (int ks = 0; ks < 2; ++ks)
      aq[mi][ks] = ld8(qlp + (mi*16 + c)*64 + ks*32 + g*8);

  f32x4 zacc[4][4] = {};
  float sl[4][4] = {};
  const u16* kp = kk + (long)bh*NTOK*DH;
  const u16* vp = vt + (long)bh*DH*NTOK;
  char* pbase = (char*)&Pl[w][0][0];
  const int tok00 = qt*1024 + w*256;

  for (int it = 0; it < 8; ++it) {
    const int t0 = tok00 + it*32;
    f32x4 sacc[4][2] = {};
    s16x8 kb[2][2];
    #pragma unroll
    for (int cg = 0; cg < 2; ++cg)
      #pragma unroll
      for (int ks = 0; ks < 2; ++ks)
        kb[cg][ks] = ld8(kp + (long)(t0 + cg*16 + c)*64 + ks*32 + g*8);
    #pragma unroll
    for (int cg = 0; cg < 2; ++cg)
      #pragma unroll
      for (int ks = 0; ks < 2; ++ks)
        #pragma unroll
        for (int mi = 0; mi < 4; ++mi)
          sacc[mi][cg] = __builtin_amdgcn_mfma_f32_16x16x32_bf16(aq[mi][ks], kb[cg][ks], sacc[mi][cg], 0, 0, 0);
    #pragma unroll
    for (int mi = 0; mi < 4; ++mi)
      #pragma unroll
      for (int r = 0; r < 4; ++r) {
        const int row = mi*16 + g*4 + r;
        const float p0 = __expf(sacc[mi][0][r]);
        const float p1 = __expf(sacc[mi][1][r]);
        sl[mi][r] += p0 + p1;
        char* base = pbase + row*80;
        *(u16*)(base + c*2)      = f2b(p0);
        *(u16*)(base + 32 + c*2) = f2b(p1);
      }
    s16x8 pa[4];
    #pragma unroll
    for (int mi = 0; mi < 4; ++mi) pa[mi] = *(const s16x8*)(pbase + (mi*16 + c)*80 + g*16);
    #pragma unroll
    for (int ni = 0; ni < 4; ++ni) {
      const s16x8 vb = ld8(vp + (long)(ni*16 + c)*NTOK + t0 + g*8);
      #pragma unroll
      for (int mi = 0; mi < 4; ++mi)
        zacc[mi][ni] = __builtin_amdgcn_mfma_f32_16x16x32_bf16(pa[mi], vb, zacc[mi][ni], 0, 0, 0);
    }
  }
  #pragma unroll
  for (int mi = 0; mi < 4; ++mi)
    #pragma unroll
    for (int r = 0; r < 4; ++r) {
      float s = sl[mi][r];
      s += __shfl_xor(s, 1); s += __shfl_xor(s, 2); s += __shfl_xor(s, 4); s += __shfl_xor(s, 8);
      sl[mi][r] = s;
    }
  #pragma unroll
  for (int mi = 0; mi < 4; ++mi)
    #pragma unroll
    for (int ni = 0; ni < 4; ++ni)
      #pragma unroll
      for (int r = 0; r < 4; ++r)
        Zl[w][mi*16 + g*4 + r][ni*16 + c] = zacc[mi][ni][r];
  if (c == 0)
    #pragma unroll
    for (int mi = 0; mi < 4; ++mi)
      #pragma unroll
      for (int r = 0; r < 4; ++r)
        Sl[w][mi*16 + g*4 + r] = sl[mi][r];
  __syncthreads();
  float* zpp = zp + (long)blockIdx.x*4096;
  for (int i = t; i < 4096; i += 256) {
    const int row = i >> 6, dh = i & 63;
    zpp[i] = Zl[0][row][dh] + Zl[1][row][dh] + Zl[2][row][dh] + Zl[3][row][dh];
  }
  if (t < 64) sp[(long)blockIdx.x*64 + t] = Sl[0][t] + Sl[1][t] + Sl[2][t] + Sl[3][t];
}

// ---------------- reduce attn3v partials -> z ----------------
__global__ __launch_bounds__(256) void k_zred(const float* __restrict__ zp, const float* __restrict__ sp,
                                              float* __restrict__ z) {
  const int bh = blockIdx.x, t = threadIdx.x;
  for (int i = t; i < 4096; i += 256) {
    const int row = i >> 6;
    float zs = 0.f, ss = 0.f;
    #pragma unroll
    for (int qt = 0; qt < 4; ++qt) {
      zs += zp[((long)(bh*4 + qt))*4096 + i];
      ss += sp[(long)(bh*4 + qt)*64 + row];
    }
    z[(long)bh*4096 + i] = zs / ss;
  }
}

// ---------------- W2^T = (attn2inv @ z)^T  (bf16 out, [dh][lm], 512 thr) ----------------
__global__ __launch_bounds__(512) void k_w2(const float* __restrict__ a2inv, const float* __restrict__ z,
                                            u16* __restrict__ w2t) {
  __shared__ __align__(16) float Ai[64*PST];
  __shared__ __align__(16) float Zi[64*PST];
  __shared__ __align__(16) float Ci[64*PST];
  const int bh = blockIdx.x, t = threadIdx.x;
  for (int i = t; i < 4096; i += 512) {
    Ai[(i>>6)*PST + (i&63)] = a2inv[(long)bh*4096 + i];
    Zi[(i>>6)*PST + (i&63)] = z[(long)bh*4096 + i];
  }
  __syncthreads();
  mm_nn8(Ai, Zi, Ci, t);
  __syncthreads();
  for (int i = t; i < 4096; i += 512) { const int r = i>>6, cc = i&63; w2t[(long)bh*4096 + cc*64 + r] = f2b(Ci[r*PST + cc]); }
}

// ---------------- out_h = softmax(q @ k_l^T) @ W2, fused, writes attnout bf16 ----------------
#define P1ST 144   /* bytes per P row */
__global__ __launch_bounds__(256) void k_attn1(const u16* __restrict__ q, const u16* __restrict__ klb,
                                               const u16* __restrict__ w2t, u16* __restrict__ ao) {
  __shared__ __align__(16) u16 Pl[4][64][72];
  const int bx = blockIdx.x, bh = bx >> 4, tt = bx & 15;
  const int b = bh >> 4, h = bh & 15;
  const int t = threadIdx.x, w = t >> 6, lane = t & 63;
  const int c = lane & 15, g = lane >> 4;
  const int tok0 = tt*256 + w*64;
  const u16* qp  = q + ((long)bh*NTOK + tok0)*DH;
  const u16* klp = klb + (long)bh*4096;
  const u16* wp  = w2t + (long)bh*4096;
  char* pbase = (char*)&Pl[w][0][0];

  s16x8 aq[4][2], kb[4][2], wb[4][2];
  #pragma unroll
  for (int i = 0; i < 4; ++i)
    #pragma unroll
    for (int ks = 0; ks < 2; ++ks) {
      aq[i][ks] = ld8(qp + (long)(i*16 + c)*DH + ks*32 + g*8);
      kb[i][ks] = ld8(klp + (i*16 + c)*64 + ks*32 + g*8);
      wb[i][ks] = ld8(wp  + (i*16 + c)*64 + ks*32 + g*8);
    }
  f32x4 sacc[4][4] = {};
  #pragma unroll
  for (int ks = 0; ks < 2; ++ks)
    #pragma unroll
    for (int mi = 0; mi < 4; ++mi)
      #pragma unroll
      for (int ni = 0; ni < 4; ++ni)
        sacc[mi][ni] = __builtin_amdgcn_mfma_f32_16x16x32_bf16(aq[mi][ks], kb[ni][ks], sacc[mi][ni], 0, 0, 0);

  float rs[4][4];
  #pragma unroll
  for (int mi = 0; mi < 4; ++mi)
    #pragma unroll
    for (int r = 0; r < 4; ++r) {
      const int row = mi*16 + g*4 + r;
      char* base = pbase + row*P1ST;
      float ssum = 0.f;
      #pragma unroll
      for (int ni = 0; ni < 4; ++ni) {
        const float p = __expf(sacc[mi][ni][r]);
        ssum += p;
        *(u16*)(base + (ni*16 + c)*2) = f2b(p);
      }
      ssum += __shfl_xor(ssum, 1); ssum += __shfl_xor(ssum, 2);
      ssum += __shfl_xor(ssum, 4); ssum += __shfl_xor(ssum, 8);
      rs[mi][r] = ssum;
    }
  __builtin_amdgcn_s_barrier();   // intra-wave store->read ordering
  s16x8 pa[4][2];
  #pragma unroll
  for (int mi = 0; mi < 4; ++mi)
    #pragma unroll
    for (int ks = 0; ks < 2; ++ks)
      pa[mi][ks] = *(const s16x8*)(pbase + (mi*16 + c)*P1ST + ks*64 + g*16);
  f32x4 oacc[4][4] = {};
  #pragma unroll
  for (int ks = 0; ks < 2; ++ks)
    #pragma unroll
    for (int mi = 0; mi < 4; ++mi)
      #pragma unroll
      for (int ni = 0; ni < 4; ++ni)
        oacc[mi][ni] = __builtin_amdgcn_mfma_f32_16x16x32_bf16(pa[mi][ks], wb[ni][ks], oacc[mi][ni], 0, 0, 0);

  u16* op = ao + (long)b*NTOK*DM + (long)h*64;
  #pragma unroll
  for (int mi = 0; mi < 4; ++mi)
    #pragma unroll
    for (int r = 0; r < 4; ++r) {
      const int tok = tok0 + mi*16 + g*4 + r;
      const float inv = 1.0f / rs[mi][r];
      #pragma unroll
      for (int ni = 0; ni < 4; ++ni)
        op[(long)tok*DM + ni*16 + c] = f2b(oacc[mi][ni][r] * inv);
    }
}

extern "C" void kernel_launch(void* const* d_in, const int* in_sizes, int n_in,
                              void* d_out, int out_size, void* d_ws, size_t ws_size,
                              hipStream_t stream) {
  const float* hs   = (const float*)d_in[0];
  const float* Wqkv = (const float*)d_in[1];
  const float* bqkv = (const float*)d_in[2];
  const float* Wout = (const float*)d_in[3];
  const float* bout = (const float*)d_in[4];
  float* out = (float*)d_out;
  char* w = (char*)d_ws;

  u16*  Xb    = (u16*)(w);                 // 32MB; free after QKV gemm
  float* zp   = (float*)(w);               // aliases Xb: written by attn3v_p (after gemm0)
  float* sp   = (float*)(w + 4194304L);    // within Xb region
  u16*  WqkvT = (u16*)(w + 33554432L);
  u16*  WoutT = (u16*)(w + 39845888L);
  u16*  q     = (u16*)(w + 41943040L);
  float* psum = (float*)(w + 41943040L);   // aliases q: consumed by k_lreduce before gemm writes q
  u16*  k     = (u16*)(w + 75497472L);
  u16*  v     = (u16*)(w + 109051904L);
  u16*  vt    = (u16*)(w + 142606336L);
  float* Xl   = (float*)(w + 142606336L);  // aliases vt: consumed before k_vtrans writes
  float* qlf  = (float*)(w + 176160768L);
  float* klf  = (float*)(w + 177209344L);
  u16*  qlb   = (u16*)(w + 178257920L);
  u16*  klb   = (u16*)(w + 178782208L);
  float* a2i  = (float*)(w + 179306496L);
  float* z    = (float*)(w + 180355072L);
  u16*  w2t   = (u16*)(w + 181403648L);
  u16*  ao    = (u16*)(w + 181927936L);

  k_cvt<<<2048, 256, 0, stream>>>(hs, Xb, 4194304L);
  k_cvt_t<<<dim3(48,16), 256, 0, stream>>>(Wqkv, WqkvT, 1024, 3072);
  k_cvt_t<<<dim3(16,16), 256, 0, stream>>>(Wout, WoutT, 1024, 1024);
  k_xlmean<<<dim3(256,4), 256, 0, stream>>>(hs, Xl);
  k_lproj2<<<dim3(8,8,8), 256, 0, stream>>>(Xl, Wqkv, psum);
  k_lreduce<<<2048, 256, 0, stream>>>(psum, bqkv, qlf, klf, qlb, klb);
  k_gemm256<0><<<dim3(64,12), 512, 0, stream>>>(Xb, WqkvT, bqkv, 3072, nullptr, q, k, v);
  k_vtrans<<<4096, 256, 0, stream>>>(v, vt);
  k_pinv<<<64, 512, 0, stream>>>(qlf, klf, a2i);
  k_attn3v_p<<<256, 256, 0, stream>>>(qlb, k, vt, zp, sp);
  k_zred<<<64, 256, 0, stream>>>(zp, sp, z);
  k_w2<<<64, 512, 0, stream>>>(a2i, z, w2t);
  k_attn1<<<1024, 256, 0, stream>>>(q, klb, w2t, ao);
  k_gemm256<1><<<dim3(64,4), 512, 0, stream>>>(ao, WoutT, bout, 1024, out, nullptr, nullptr, nullptr);
}

// Round 6
// 364.624 us; speedup vs baseline: 1.7747x; 1.0283x over previous
//
#include <hip/hip_runtime.h>
#include <cstdint>

typedef unsigned short u16;
typedef __attribute__((ext_vector_type(8))) short s16x8;
typedef __attribute__((ext_vector_type(4))) float f32x4;

#define NTOK 4096
#define DH   64
#define DM   1024
#define NH   16

static __device__ __forceinline__ float b2f(u16 u){ return __uint_as_float(((unsigned)u)<<16); }
static __device__ __forceinline__ u16 f2b(float f){
  unsigned u = __float_as_uint(f);
  return (u16)((u + 0x7FFFu + ((u>>16)&1u)) >> 16);   // RNE
}

static __device__ __forceinline__ void gload_lds16(const void* g, void* l) {
  __builtin_amdgcn_global_load_lds(
      (const __attribute__((address_space(1))) unsigned*)(uintptr_t)g,
      (__attribute__((address_space(3))) unsigned*)(uintptr_t)l, 16, 0, 0);
}

static __device__ __forceinline__ s16x8 ld8(const u16* p){ return *(const s16x8*)(const void*)p; }

// ---------------- fused: hs -> bf16 Xb  AND  landmark means Xl (fp32) ----------------
__global__ __launch_bounds__(256) void k_cvt_xl(const float* __restrict__ hs, u16* __restrict__ Xb,
                                                float* __restrict__ Xl) {
  const int grp = blockIdx.x;                 // b*64 + lm (64-token group)
  const int d = blockIdx.y*256 + threadIdx.x;
  const float* p = hs + (long)grp*64*DM + d;
  u16* xo = Xb + (long)grp*64*DM + d;
  float s = 0.f;
  #pragma unroll 8
  for (int i = 0; i < 64; ++i) {
    const float v = p[(long)i*DM];
    s += v;
    xo[(long)i*DM] = f2b(v);
  }
  Xl[(long)grp*DM + d] = s * (1.0f/64.0f);
}

// ---------------- convert+transpose: f32 [R][C] -> bf16 [C][R] ----------------
__global__ __launch_bounds__(256) void k_cvt_t(const float* __restrict__ in, u16* __restrict__ out, int R, int C) {
  __shared__ float tile[64][65];
  const int tc = blockIdx.x, tr = blockIdx.y;
  const int t = threadIdx.x, cx = t & 63, ry = t >> 6;
  #pragma unroll
  for (int p = 0; p < 16; ++p) {
    const int row = p*4 + ry;
    tile[row][cx] = in[(long)(tr*64 + row)*C + tc*64 + cx];
  }
  __syncthreads();
  #pragma unroll
  for (int p = 0; p < 16; ++p) {
    const int orow = p*4 + ry;
    out[(long)(tc*64 + orow)*R + tr*64 + cx] = f2b(tile[cx][orow]);
  }
}

// ---------------- fp32 projection, K-split: psum[z][row][col] partials ----------------
__global__ __launch_bounds__(256) void k_lproj2(const float* __restrict__ Xl, const float* __restrict__ Wqkv,
                                                float* __restrict__ psum) {
  __shared__ __align__(16) float Xs[32][68];
  const int t = threadIdx.x;
  const int wcol = blockIdx.x*256 + t;    // 0..2047
  const int r0 = blockIdx.y*32;
  const int kbase = blockIdx.z*128;
  float acc[32];
  #pragma unroll
  for (int r = 0; r < 32; ++r) acc[r] = 0.f;
  for (int k0 = kbase; k0 < kbase + 128; k0 += 64) {
    __syncthreads();
    for (int idx = t; idx < 2048; idx += 256)
      Xs[idx>>6][idx&63] = Xl[(long)(r0 + (idx>>6))*DM + k0 + (idx&63)];
    __syncthreads();
    for (int kk = 0; kk < 64; kk += 4) {
      f32x4 wv;
      #pragma unroll
      for (int j = 0; j < 4; ++j) wv[j] = Wqkv[(long)(k0+kk+j)*3072 + wcol];
      #pragma unroll
      for (int r = 0; r < 32; ++r) {
        const f32x4 xv = *(const f32x4*)&Xs[r][kk];
        acc[r] += xv[0]*wv[0] + xv[1]*wv[1] + xv[2]*wv[2] + xv[3]*wv[3];
      }
    }
  }
  float* po = psum + ((long)blockIdx.z*256 + r0)*2048 + wcol;
  #pragma unroll
  for (int r = 0; r < 32; ++r) po[(long)r*2048] = acc[r];
}

// ---------------- reduce K-slices + bias + scale -> qlf/klf/qlb/klb ----------------
__global__ __launch_bounds__(256) void k_lreduce(const float* __restrict__ psum, const float* __restrict__ bqkv,
                                                 float* __restrict__ qlf, float* __restrict__ klf,
                                                 u16* __restrict__ qlb, u16* __restrict__ klb) {
  const long idx = (long)blockIdx.x*256 + threadIdx.x;   // 0..524287
  const int row = (int)(idx >> 11), col = (int)(idx & 2047);
  float s = 0.f;
  #pragma unroll
  for (int z = 0; z < 8; ++z) s += psum[((long)z*256 + row)*2048 + col];
  const int isq = (col < 1024) ? 1 : 0;
  float val = s + bqkv[col];
  if (isq) val *= 0.125f;
  const int b = row >> 6, lm = row & 63;
  const int c2 = col & 1023, h = c2 >> 6, dh = c2 & 63;
  const long o = (((long)b*NH + h)*64 + lm)*64 + dh;
  if (isq) { qlf[o] = val; qlb[o] = f2b(val); }
  else     { klf[o] = val; klb[o] = f2b(val); }
}

// ---------------- GEMM 256x256, BK=32, 8 waves, 4-deep LDS ring ----------------
// Software-pipelined: each 16-MFMA burst overlaps the NEXT phase's ds_reads.
// Ring/vmcnt/barrier ledger identical to the verified round-5 version:
//   stage(kt+3) issued at top of kt (after barrier kt-1, all reads of that buf drained);
//   vmcnt(8/4/0) + barrier mid-iteration retires stage(kt+1) before buf[kt+1] reads.
// LDS swizzle: source chunk ^ (row>>1)&3, read offset g ^ (c>>1)&3 (conflict-free, r5-verified).
template<int EPI>
__global__ __launch_bounds__(512, 2) void k_gemm256(
    const u16* __restrict__ A, const u16* __restrict__ Bt, const float* __restrict__ bias,
    int N, float* __restrict__ outF, u16* __restrict__ outQ, u16* __restrict__ outK, u16* __restrict__ outV)
{
  __shared__ __align__(16) u16 lds[4*16384];
  const int K = 1024;
  const int t = threadIdx.x;
  const int lane = t & 63;
  const int wid = t >> 6;
  const int c = lane & 15, g = lane >> 4;
  const int wm = wid >> 2, wn = wid & 3;
  const long arow0 = (long)blockIdx.x * 256;
  const long brow0 = (long)blockIdx.y * 256;
  char* ldsb = (char*)lds;

  const int srow = t >> 2;
  const int schunk = (t & 3) ^ ((srow >> 1) & 3);
  const u16* gA0 = A  + (arow0 + srow)*K       + schunk*8;
  const u16* gA1 = A  + (arow0 + 128 + srow)*K + schunk*8;
  const u16* gB0 = Bt + (brow0 + srow)*K       + schunk*8;
  const u16* gB1 = Bt + (brow0 + 128 + srow)*K + schunk*8;
  const int dstoff = t*16;

#define STAGE_A(kt) { char* bse = ldsb + ((kt)&3)*32768; \
    gload_lds16(gA0 + (kt)*32, bse + dstoff); \
    gload_lds16(gA1 + (kt)*32, bse + 8192 + dstoff); }
#define STAGE_B(kt) { char* bse = ldsb + ((kt)&3)*32768 + 16384; \
    gload_lds16(gB0 + (kt)*32, bse + dstoff); \
    gload_lds16(gB1 + (kt)*32, bse + 8192 + dstoff); }

  const int gs = g ^ ((c >> 1) & 3);
  int aoff[2][4], boff[4];
  #pragma unroll
  for (int mi = 0; mi < 4; ++mi) {
    aoff[0][mi] = (0*128 + wm*64 + mi*16 + c)*64 + gs*16;
    aoff[1][mi] = (1*128 + wm*64 + mi*16 + c)*64 + gs*16;
    boff[mi]    = 16384 + (wn*64 + mi*16 + c)*64 + gs*16;
  }

  f32x4 acc0[4][4] = {};
  f32x4 acc1[4][4] = {};

  // prologue: stage K-tiles 0,1,2; wait tile 0; issue initial af/bfr reads
  STAGE_A(0); STAGE_B(0); STAGE_A(1); STAGE_B(1); STAGE_A(2); STAGE_B(2);
  asm volatile("s_waitcnt vmcnt(8)" ::: "memory");
  __builtin_amdgcn_s_barrier();

  s16x8 af[4], bfr[4], af2[4];
  #pragma unroll
  for (int mi = 0; mi < 4; ++mi) af[mi]  = *(const s16x8*)(ldsb + aoff[0][mi]);
  #pragma unroll
  for (int ni = 0; ni < 4; ++ni) bfr[ni] = *(const s16x8*)(ldsb + boff[ni]);

  for (int kt = 0; kt < 32; ++kt) {
    char* buf  = ldsb + (kt&3)*32768;
    char* bufn = ldsb + ((kt+1)&3)*32768;
    if (kt + 3 < 32) { STAGE_A(kt+3) STAGE_B(kt+3) }
    // drain af/bfr (issued last iteration), then issue af2 under acc0's MFMAs
    asm volatile("s_waitcnt lgkmcnt(0)" ::: "memory");
    __builtin_amdgcn_sched_barrier(0);
    #pragma unroll
    for (int mi = 0; mi < 4; ++mi) af2[mi] = *(const s16x8*)(buf + aoff[1][mi]);
    __builtin_amdgcn_sched_barrier(0);
    __builtin_amdgcn_s_setprio(1);
    #pragma unroll
    for (int mi = 0; mi < 4; ++mi)
      #pragma unroll
      for (int ni = 0; ni < 4; ++ni)
        acc0[mi][ni] = __builtin_amdgcn_mfma_f32_16x16x32_bf16(af[mi], bfr[ni], acc0[mi][ni], 0, 0, 0);
    __builtin_amdgcn_s_setprio(0);
    // drain af2; retire stage kt+1; barrier; issue next-tile af/bfr under acc1's MFMAs
    asm volatile("s_waitcnt lgkmcnt(0)" ::: "memory");
    __builtin_amdgcn_sched_barrier(0);
    if (kt <= 28)      { asm volatile("s_waitcnt vmcnt(8)" ::: "memory"); }
    else if (kt == 29) { asm volatile("s_waitcnt vmcnt(4)" ::: "memory"); }
    else if (kt == 30) { asm volatile("s_waitcnt vmcnt(0)" ::: "memory"); }
    if (kt < 31) __builtin_amdgcn_s_barrier();
    s16x8 nf[4], nb[4];
    if (kt < 31) {
      #pragma unroll
      for (int mi = 0; mi < 4; ++mi) nf[mi] = *(const s16x8*)(bufn + aoff[0][mi]);
      #pragma unroll
      for (int ni = 0; ni < 4; ++ni) nb[ni] = *(const s16x8*)(bufn + boff[ni]);
    }
    __builtin_amdgcn_sched_barrier(0);
    __builtin_amdgcn_s_setprio(1);
    #pragma unroll
    for (int mi = 0; mi < 4; ++mi)
      #pragma unroll
      for (int ni = 0; ni < 4; ++ni)
        acc1[mi][ni] = __builtin_amdgcn_mfma_f32_16x16x32_bf16(af2[mi], bfr[ni], acc1[mi][ni], 0, 0, 0);
    __builtin_amdgcn_s_setprio(0);
    if (kt < 31) {
      #pragma unroll
      for (int mi = 0; mi < 4; ++mi) { af[mi] = nf[mi]; bfr[mi] = nb[mi]; }
    }
  }
#undef STAGE_A
#undef STAGE_B

  if (EPI == 0) {
    const int tensor = (int)(brow0 >> 10);
    u16* dst = (tensor == 0) ? outQ : (tensor == 1) ? outK : outV;
    const float mul = (tensor == 0) ? 0.125f : 1.0f;
    #pragma unroll
    for (int ph = 0; ph < 2; ++ph)
      #pragma unroll
      for (int mi = 0; mi < 4; ++mi) {
        const int rowb = ph*128 + wm*64 + mi*16 + g*4;
        #pragma unroll
        for (int ni = 0; ni < 4; ++ni) {
          const long gcol = brow0 + wn*64 + ni*16 + c;
          const int c2 = (int)(gcol & 1023);
          const int head = c2 >> 6, dh = c2 & 63;
          const float bv = bias[gcol];
          const f32x4 a = ph ? acc1[mi][ni] : acc0[mi][ni];
          #pragma unroll
          for (int r = 0; r < 4; ++r) {
            const long grow = arow0 + rowb + r;
            const int b = (int)(grow >> 12), tok = (int)(grow & 4095);
            dst[(((long)b*NH + head)*NTOK + tok)*DH + dh] = f2b((a[r] + bv)*mul);
          }
        }
      }
  } else {
    #pragma unroll
    for (int ph = 0; ph < 2; ++ph)
      #pragma unroll
      for (int mi = 0; mi < 4; ++mi) {
        const int rowb = ph*128 + wm*64 + mi*16 + g*4;
        #pragma unroll
        for (int ni = 0; ni < 4; ++ni) {
          const long gcol = brow0 + wn*64 + ni*16 + c;
          const float bv = bias[gcol];
          const f32x4 a = ph ? acc1[mi][ni] : acc0[mi][ni];
          #pragma unroll
          for (int r = 0; r < 4; ++r) {
            const long grow = arow0 + rowb + r;
            outF[grow*N + gcol] = a[r] + bv;
          }
        }
      }
  }
}

// ---------------- v transpose: [bh][tok][dh] -> [bh][dh][tok] ----------------
__global__ __launch_bounds__(256) void k_vtrans(const u16* __restrict__ v, u16* __restrict__ vt) {
  __shared__ u16 tile[64][65];
  const int bh = blockIdx.x >> 6, tt = blockIdx.x & 63;
  const int t = threadIdx.x, cx = t & 63, ry = t >> 6;
  const u16* vp = v + ((long)bh*NTOK + tt*64)*DH;
  #pragma unroll
  for (int p = 0; p < 16; ++p) { const int row = p*4 + ry; tile[row][cx] = vp[row*DH + cx]; }
  __syncthreads();
  u16* op = vt + (long)bh*DH*NTOK + tt*64;
  #pragma unroll
  for (int p = 0; p < 16; ++p) { const int orow = p*4 + ry; op[(long)orow*NTOK + cx] = tile[cx][orow]; }
}

// ---------------- fp32 LDS 64x64 matmul helpers, 512 threads (8 cols/thread) ----------------
#define PST 68
static __device__ __forceinline__ void mm_nn8(const float* A, const float* B, float* C, int t) {
  const int lane = t & 63, j0 = (t >> 6) << 3;
  float acc[8];
  #pragma unroll
  for (int j = 0; j < 8; ++j) acc[j] = 0.f;
  for (int k = 0; k < 64; k += 4) {
    const f32x4 a4 = *(const f32x4*)&A[lane*PST + k];
    #pragma unroll
    for (int dk = 0; dk < 4; ++dk) {
      const float a = a4[dk];
      const float* br = &B[(k + dk)*PST + j0];
      const f32x4 b0 = *(const f32x4*)(br);
      const f32x4 b1 = *(const f32x4*)(br + 4);
      #pragma unroll
      for (int qq = 0; qq < 4; ++qq) { acc[qq] += a*b0[qq]; acc[4+qq] += a*b1[qq]; }
    }
  }
  #pragma unroll
  for (int j = 0; j < 8; ++j) C[lane*PST + j0 + j] = acc[j];
}
static __device__ __forceinline__ void mm_nt8(const float* A, const float* B, float* C, int t) {
  const int lane = t & 63, j0 = (t >> 6) << 3;
  float acc[8];
  #pragma unroll
  for (int j = 0; j < 8; ++j) acc[j] = 0.f;
  for (int k = 0; k < 64; k += 4) {
    const f32x4 a4 = *(const f32x4*)&A[lane*PST + k];
    #pragma unroll
    for (int jj = 0; jj < 8; ++jj) {
      const f32x4 b4 = *(const f32x4*)&B[(j0 + jj)*PST + k];
      acc[jj] += a4[0]*b4[0] + a4[1]*b4[1] + a4[2]*b4[2] + a4[3]*b4[3];
    }
  }
  #pragma unroll
  for (int j = 0; j < 8; ++j) C[lane*PST + j0 + j] = acc[j];
}

// ---------------- sim2 + softmax + Newton-Schulz pinv (all fp32, 512 thr) ----------------
__global__ __launch_bounds__(512) void k_pinv(const float* __restrict__ qlf, const float* __restrict__ klf,
                                              float* __restrict__ a2inv) {
  __shared__ __align__(16) float Xb[64*PST];
  __shared__ __align__(16) float Vb[64*PST];
  __shared__ __align__(16) float T1[64*PST];
  __shared__ __align__(16) float T2[64*PST];
  __shared__ __align__(16) float T3[64*PST];
  const int bh = blockIdx.x, t = threadIdx.x;
  const float* ql = qlf + (long)bh*4096;
  const float* kl = klf + (long)bh*4096;
  for (int i = t; i < 4096; i += 512) { T1[(i>>6)*PST + (i&63)] = ql[i]; T2[(i>>6)*PST + (i&63)] = kl[i]; }
  __syncthreads();
  mm_nt8(T1, T2, Xb, t);          // sim2 = q_l @ k_l^T
  __syncthreads();
  if (t < 64) {                   // row softmax (precise exp on the chaotic path)
    float mx = -1e30f;
    for (int j = 0; j < 64; ++j) mx = fmaxf(mx, Xb[t*PST + j]);
    float s = 0.f;
    for (int j = 0; j < 64; ++j) { const float e = expf(Xb[t*PST + j] - mx); Xb[t*PST + j] = e; s += e; }
    const float inv = 1.0f/s;
    for (int j = 0; j < 64; ++j) Xb[t*PST + j] *= inv;
  }
  __syncthreads();
  for (int i = t; i < 4096; i += 512) { const int r = i>>6, cc = i&63; Vb[r*PST+cc] = Xb[r*PST+cc]; }
  __syncthreads();
  for (int it = 0; it < 6; ++it) {
    mm_nn8(Xb, Vb, T1, t);  __syncthreads();                 // KV
    for (int i = t; i < 4096; i += 512) { const int r=i>>6, cc=i&63; T2[r*PST+cc] = (r==cc?7.0f:0.0f) - T1[r*PST+cc]; }
    __syncthreads();
    mm_nn8(T1, T2, T3, t);  __syncthreads();                 // KV@(7I-KV)
    for (int i = t; i < 4096; i += 512) { const int r=i>>6, cc=i&63; T2[r*PST+cc] = (r==cc?15.0f:0.0f) - T3[r*PST+cc]; }
    __syncthreads();
    mm_nn8(T1, T2, T3, t);  __syncthreads();                 // KV@(15I-...)
    for (int i = t; i < 4096; i += 512) { const int r=i>>6, cc=i&63; T2[r*PST+cc] = (r==cc?13.0f:0.0f) - T3[r*PST+cc]; }
    __syncthreads();
    mm_nn8(Vb, T2, T3, t);  __syncthreads();                 // V@(13I-...)
    for (int i = t; i < 4096; i += 512) { const int r=i>>6, cc=i&63; Vb[r*PST+cc] = 0.25f*T3[r*PST+cc]; }
    __syncthreads();
  }
  for (int i = t; i < 4096; i += 512) a2inv[(long)bh*4096 + i] = Vb[(i>>6)*PST + (i&63)];
}

// ---------------- attn3 @ v partials: 4 blocks per (b,h), 1024 tokens each ----------------
__global__ __launch_bounds__(256) void k_attn3v_p(const u16* __restrict__ qlb, const u16* __restrict__ kk,
                                                  const u16* __restrict__ vt,
                                                  float* __restrict__ zp, float* __restrict__ sp) {
  __shared__ __align__(16) float Zl[4][64][64];
  __shared__ float Sl[4][64];
  __shared__ __align__(16) u16 Pl[4][64][40];   // rows padded to 80B (32 cols used)
  const int bh = blockIdx.x >> 2, qt = blockIdx.x & 3;
  const int t = threadIdx.x, w = t >> 6, lane = t & 63;
  const int c = lane & 15, g = lane >> 4;

  s16x8 aq[4][2];
  const u16* qlp = qlb + (long)bh*4096;
  #pragma unroll
  for (int mi = 0; mi < 4; ++mi)
    #pragma unroll
    for (int ks = 0; ks < 2; ++ks)
      aq[mi][ks] = ld8(qlp + (mi*16 + c)*64 + ks*32 + g*8);

  f32x4 zacc[4][4] = {};
  float sl[4][4] = {};
  const u16* kp = kk + (long)bh*NTOK*DH;
  const u16* vp = vt + (long)bh*DH*NTOK;
  char* pbase = (char*)&Pl[w][0][0];
  const int tok00 = qt*1024 + w*256;

  for (int it = 0; it < 8; ++it) {
    const int t0 = tok00 + it*32;
    f32x4 sacc[4][2] = {};
    s16x8 kb[2][2];
    #pragma unroll
    for (int cg = 0; cg < 2; ++cg)
      #pragma unroll
      for (int ks = 0; ks < 2; ++ks)
        kb[cg][ks] = ld8(kp + (long)(t0 + cg*16 + c)*64 + ks*32 + g*8);
    #pragma unroll
    for (int cg = 0; cg < 2; ++cg)
      #pragma unroll
      for (int ks = 0; ks < 2; ++ks)
        #pragma unroll
        for (int mi = 0; mi < 4; ++mi)
          sacc[mi][cg] = __builtin_amdgcn_mfma_f32_16x16x32_bf16(aq[mi][ks], kb[cg][ks], sacc[mi][cg], 0, 0, 0);
    #pragma unroll
    for (int mi = 0; mi < 4; ++mi)
      #pragma unroll
      for (int r = 0; r < 4; ++r) {
        const int row = mi*16 + g*4 + r;
        const float p0 = __expf(sacc[mi][0][r]);
        const float p1 = __expf(sacc[mi][1][r]);
        sl[mi][r] += p0 + p1;
        char* base = pbase + row*80;
        *(u16*)(base + c*2)      = f2b(p0);
        *(u16*)(base + 32 + c*2) = f2b(p1);
      }
    s16x8 pa[4];
    #pragma unroll
    for (int mi = 0; mi < 4; ++mi) pa[mi] = *(const s16x8*)(pbase + (mi*16 + c)*80 + g*16);
    #pragma unroll
    for (int ni = 0; ni < 4; ++ni) {
      const s16x8 vb = ld8(vp + (long)(ni*16 + c)*NTOK + t0 + g*8);
      #pragma unroll
      for (int mi = 0; mi < 4; ++mi)
        zacc[mi][ni] = __builtin_amdgcn_mfma_f32_16x16x32_bf16(pa[mi], vb, zacc[mi][ni], 0, 0, 0);
    }
  }
  #pragma unroll
  for (int mi = 0; mi < 4; ++mi)
    #pragma unroll
    for (int r = 0; r < 4; ++r) {
      float s = sl[mi][r];
      s += __shfl_xor(s, 1); s += __shfl_xor(s, 2); s += __shfl_xor(s, 4); s += __shfl_xor(s, 8);
      sl[mi][r] = s;
    }
  #pragma unroll
  for (int mi = 0; mi < 4; ++mi)
    #pragma unroll
    for (int ni = 0; ni < 4; ++ni)
      #pragma unroll
      for (int r = 0; r < 4; ++r)
        Zl[w][mi*16 + g*4 + r][ni*16 + c] = zacc[mi][ni][r];
  if (c == 0)
    #pragma unroll
    for (int mi = 0; mi < 4; ++mi)
      #pragma unroll
      for (int r = 0; r < 4; ++r)
        Sl[w][mi*16 + g*4 + r] = sl[mi][r];
  __syncthreads();
  float* zpp = zp + (long)blockIdx.x*4096;
  for (int i = t; i < 4096; i += 256) {
    const int row = i >> 6, dh = i & 63;
    zpp[i] = Zl[0][row][dh] + Zl[1][row][dh] + Zl[2][row][dh] + Zl[3][row][dh];
  }
  if (t < 64) sp[(long)blockIdx.x*64 + t] = Sl[0][t] + Sl[1][t] + Sl[2][t] + Sl[3][t];
}

// ---------------- reduce attn3v partials -> z ----------------
__global__ __launch_bounds__(256) void k_zred(const float* __restrict__ zp, const float* __restrict__ sp,
                                              float* __restrict__ z) {
  const int bh = blockIdx.x, t = threadIdx.x;
  for (int i = t; i < 4096; i += 256) {
    const int row = i >> 6;
    float zs = 0.f, ss = 0.f;
    #pragma unroll
    for (int qt = 0; qt < 4; ++qt) {
      zs += zp[((long)(bh*4 + qt))*4096 + i];
      ss += sp[(long)(bh*4 + qt)*64 + row];
    }
    z[(long)bh*4096 + i] = zs / ss;
  }
}

// ---------------- W2^T = (attn2inv @ z)^T  (bf16 out, [dh][lm], 512 thr) ----------------
__global__ __launch_bounds__(512) void k_w2(const float* __restrict__ a2inv, const float* __restrict__ z,
                                            u16* __restrict__ w2t) {
  __shared__ __align__(16) float Ai[64*PST];
  __shared__ __align__(16) float Zi[64*PST];
  __shared__ __align__(16) float Ci[64*PST];
  const int bh = blockIdx.x, t = threadIdx.x;
  for (int i = t; i < 4096; i += 512) {
    Ai[(i>>6)*PST + (i&63)] = a2inv[(long)bh*4096 + i];
    Zi[(i>>6)*PST + (i&63)] = z[(long)bh*4096 + i];
  }
  __syncthreads();
  mm_nn8(Ai, Zi, Ci, t);
  __syncthreads();
  for (int i = t; i < 4096; i += 512) { const int r = i>>6, cc = i&63; w2t[(long)bh*4096 + cc*64 + r] = f2b(Ci[r*PST + cc]); }
}

// ---------------- out_h = softmax(q @ k_l^T) @ W2, fused, writes attnout bf16 ----------------
#define P1ST 144   /* bytes per P row */
__global__ __launch_bounds__(256) void k_attn1(const u16* __restrict__ q, const u16* __restrict__ klb,
                                               const u16* __restrict__ w2t, u16* __restrict__ ao) {
  __shared__ __align__(16) u16 Pl[4][64][72];
  const int bx = blockIdx.x, bh = bx >> 4, tt = bx & 15;
  const int b = bh >> 4, h = bh & 15;
  const int t = threadIdx.x, w = t >> 6, lane = t & 63;
  const int c = lane & 15, g = lane >> 4;
  const int tok0 = tt*256 + w*64;
  const u16* qp  = q + ((long)bh*NTOK + tok0)*DH;
  const u16* klp = klb + (long)bh*4096;
  const u16* wp  = w2t + (long)bh*4096;
  char* pbase = (char*)&Pl[w][0][0];

  s16x8 aq[4][2], kb[4][2], wb[4][2];
  #pragma unroll
  for (int i = 0; i < 4; ++i)
    #pragma unroll
    for (int ks = 0; ks < 2; ++ks) {
      aq[i][ks] = ld8(qp + (long)(i*16 + c)*DH + ks*32 + g*8);
      kb[i][ks] = ld8(klp + (i*16 + c)*64 + ks*32 + g*8);
      wb[i][ks] = ld8(wp  + (i*16 + c)*64 + ks*32 + g*8);
    }
  f32x4 sacc[4][4] = {};
  #pragma unroll
  for (int ks = 0; ks < 2; ++ks)
    #pragma unroll
    for (int mi = 0; mi < 4; ++mi)
      #pragma unroll
      for (int ni = 0; ni < 4; ++ni)
        sacc[mi][ni] = __builtin_amdgcn_mfma_f32_16x16x32_bf16(aq[mi][ks], kb[ni][ks], sacc[mi][ni], 0, 0, 0);

  float rs[4][4];
  #pragma unroll
  for (int mi = 0; mi < 4; ++mi)
    #pragma unroll
    for (int r = 0; r < 4; ++r) {
      const int row = mi*16 + g*4 + r;
      char* base = pbase + row*P1ST;
      float ssum = 0.f;
      #pragma unroll
      for (int ni = 0; ni < 4; ++ni) {
        const float p = __expf(sacc[mi][ni][r]);
        ssum += p;
        *(u16*)(base + (ni*16 + c)*2) = f2b(p);
      }
      ssum += __shfl_xor(ssum, 1); ssum += __shfl_xor(ssum, 2);
      ssum += __shfl_xor(ssum, 4); ssum += __shfl_xor(ssum, 8);
      rs[mi][r] = ssum;
    }
  __builtin_amdgcn_s_barrier();   // intra-wave store->read ordering
  s16x8 pa[4][2];
  #pragma unroll
  for (int mi = 0; mi < 4; ++mi)
    #pragma unroll
    for (int ks = 0; ks < 2; ++ks)
      pa[mi][ks] = *(const s16x8*)(pbase + (mi*16 + c)*P1ST + ks*64 + g*16);
  f32x4 oacc[4][4] = {};
  #pragma unroll
  for (int ks = 0; ks < 2; ++ks)
    #pragma unroll
    for (int mi = 0; mi < 4; ++mi)
      #pragma unroll
      for (int ni = 0; ni < 4; ++ni)
        oacc[mi][ni] = __builtin_amdgcn_mfma_f32_16x16x32_bf16(pa[mi][ks], wb[ni][ks], oacc[mi][ni], 0, 0, 0);

  u16* op = ao + (long)b*NTOK*DM + (long)h*64;
  #pragma unroll
  for (int mi = 0; mi < 4; ++mi)
    #pragma unroll
    for (int r = 0; r < 4; ++r) {
      const int tok = tok0 + mi*16 + g*4 + r;
      const float inv = 1.0f / rs[mi][r];
      #pragma unroll
      for (int ni = 0; ni < 4; ++ni)
        op[(long)tok*DM + ni*16 + c] = f2b(oacc[mi][ni][r] * inv);
    }
}

extern "C" void kernel_launch(void* const* d_in, const int* in_sizes, int n_in,
                              void* d_out, int out_size, void* d_ws, size_t ws_size,
                              hipStream_t stream) {
  const float* hs   = (const float*)d_in[0];
  const float* Wqkv = (const float*)d_in[1];
  const float* bqkv = (const float*)d_in[2];
  const float* Wout = (const float*)d_in[3];
  const float* bout = (const float*)d_in[4];
  float* out = (float*)d_out;
  char* w = (char*)d_ws;

  u16*  Xb    = (u16*)(w);                 // 32MB; free after QKV gemm
  float* zp   = (float*)(w);               // aliases Xb: written by attn3v_p (after gemm0)
  float* sp   = (float*)(w + 4194304L);    // within Xb region
  u16*  WqkvT = (u16*)(w + 33554432L);
  u16*  WoutT = (u16*)(w + 39845888L);
  u16*  q     = (u16*)(w + 41943040L);
  float* psum = (float*)(w + 41943040L);   // aliases q: consumed by k_lreduce before gemm writes q
  u16*  k     = (u16*)(w + 75497472L);
  u16*  v     = (u16*)(w + 109051904L);
  u16*  vt    = (u16*)(w + 142606336L);
  float* Xl   = (float*)(w + 142606336L);  // aliases vt: consumed before k_vtrans writes
  float* qlf  = (float*)(w + 176160768L);
  float* klf  = (float*)(w + 177209344L);
  u16*  qlb   = (u16*)(w + 178257920L);
  u16*  klb   = (u16*)(w + 178782208L);
  float* a2i  = (float*)(w + 179306496L);
  float* z    = (float*)(w + 180355072L);
  u16*  w2t   = (u16*)(w + 181403648L);
  u16*  ao    = (u16*)(w + 181927936L);

  k_cvt_xl<<<dim3(256,4), 256, 0, stream>>>(hs, Xb, Xl);
  k_cvt_t<<<dim3(48,16), 256, 0, stream>>>(Wqkv, WqkvT, 1024, 3072);
  k_cvt_t<<<dim3(16,16), 256, 0, stream>>>(Wout, WoutT, 1024, 1024);
  k_lproj2<<<dim3(8,8,8), 256, 0, stream>>>(Xl, Wqkv, psum);
  k_lreduce<<<2048, 256, 0, stream>>>(psum, bqkv, qlf, klf, qlb, klb);
  k_gemm256<0><<<dim3(64,12), 512, 0, stream>>>(Xb, WqkvT, bqkv, 3072, nullptr, q, k, v);
  k_vtrans<<<4096, 256, 0, stream>>>(v, vt);
  k_pinv<<<64, 512, 0, stream>>>(qlf, klf, a2i);
  k_attn3v_p<<<256, 256, 0, stream>>>(qlb, k, vt, zp, sp);
  k_zred<<<64, 256, 0, stream>>>(zp, sp, z);
  k_w2<<<64, 512, 0, stream>>>(a2i, z, w2t);
  k_attn1<<<1024, 256, 0, stream>>>(q, klb, w2t, ao);
  k_gemm256<1><<<dim3(64,4), 512, 0, stream>>>(ao, WoutT, bout, 1024, out, nullptr, nullptr, nullptr);
}